// Round 2
// baseline (493.524 us; speedup 1.0000x reference)
//
#include <hip/hip_runtime.h>
#include <math.h>

#define N 8192
#define M 8192
#define C 96
#define OUT 20
#define LG 2048

#define KP2 192     // stored K per row: [hi(96)|lo(96)] fp16, 24 h8 slots
#define NSPA 4      // y-slices pass A (256 blocks = 1/CU)
#define NSPB 4      // y-slices pass B (256 blocks = 1/CU)

typedef _Float16 h8 __attribute__((ext_vector_type(8)));
typedef float    f4 __attribute__((ext_vector_type(4)));

// async global->LDS, 16B per lane, no VGPR round-trip (m97 path)
__device__ __forceinline__ void gl_lds16(const h8* g, h8* l) {
    __builtin_amdgcn_global_load_lds(
        (const __attribute__((address_space(1))) unsigned int*)g,
        (__attribute__((address_space(3))) unsigned int*)l,
        16, 0, 0);
}

// tile-slot-major h8 index: rows grouped in 128-row tiles, slot-major inside
__device__ __forceinline__ size_t tsm24(int row, int slot) {
    return ((size_t)(row >> 7) * 24 + slot) * 128 + (row & 127);
}

// ---------------- workspace layout (bytes, all 256-aligned) ----------------
constexpr size_t OFF_DIFF  = 0;
constexpr size_t OFF_AL    = 256;
constexpr size_t OFF_NMF2  = OFF_AL    + (size_t)M*3*4;
constexpr size_t OFF_UPDF  = OFF_NMF2  + (size_t)N*4;
constexpr size_t OFF_GTC   = OFF_UPDF  + (size_t)M*4;
constexpr size_t OFF_SMI   = OFF_GTC   + (size_t)M*4;
constexpr size_t OFF_PERM  = OFF_SMI   + (size_t)M*4;
constexpr size_t OFF_AP    = OFF_PERM  + (size_t)M*4;            // M x 192 fp16 (tsm24)
constexpr size_t OFF_BQ    = OFF_AP    + (size_t)M*KP2*2;        // N x 192 fp16
constexpr size_t OFF_MFP   = OFF_BQ    + (size_t)N*KP2*2;        // N x 192 fp16
constexpr size_t OFF_MIDQ  = OFF_MFP   + (size_t)N*KP2*2;        // (M+256) x 192 fp16
constexpr size_t OFF_PAV   = OFF_MIDQ  + (size_t)(M+256)*KP2*2;  // NSPA x M
constexpr size_t OFF_PAI   = OFF_PAV   + (size_t)NSPA*M*4;
constexpr size_t OFF_PB    = OFF_PAI   + (size_t)NSPA*M*4;       // NSPB x N x 20
constexpr size_t OFF_VALS  = OFF_PB    + (size_t)NSPB*N*OUT*4;
constexpr size_t OFF_POS   = OFF_VALS  + (size_t)LG*4;
constexpr size_t OFF_MAXV  = OFF_POS   + (size_t)N*4;
constexpr size_t OFF_AMAX  = OFF_MAXV  + (size_t)N*4;
constexpr size_t OFF_FLAGS = OFF_AMAX  + (size_t)N*4;
constexpr size_t OFF_CNT   = OFF_FLAGS + 256;
constexpr size_t OFF_META  = OFF_CNT   + 256;   // [0]=Mact [1]=nmacro [2..21]=cursor
constexpr size_t OFF_ORIP  = OFF_META  + 256;                    // N x float4 {x,y,z,0}
constexpr size_t OFF_SIDEQ = OFF_ORIP  + (size_t)N*16;           // (M+256) x float4 {n2,x,y,z}
constexpr size_t OFF_SIDEC = OFF_SIDEQ + (size_t)(M+256)*16;     // (M+256) int cls

// ---------------------------------------------------------------- 4x4 inverse
__global__ void k_diff(const float* __restrict__ posses, float* __restrict__ diff) {
    if (threadIdx.x != 0 || blockIdx.x != 0) return;
    float a[4][8];
    for (int i = 0; i < 4; i++)
        for (int j = 0; j < 4; j++) {
            a[i][j]     = posses[16 + i*4 + j];
            a[i][4 + j] = (i == j) ? 1.f : 0.f;
        }
    for (int col = 0; col < 4; col++) {
        int piv = col; float mx = fabsf(a[col][col]);
        for (int r = col + 1; r < 4; r++) {
            float v = fabsf(a[r][col]);
            if (v > mx) { mx = v; piv = r; }
        }
        if (piv != col)
            for (int j = 0; j < 8; j++) { float t = a[col][j]; a[col][j] = a[piv][j]; a[piv][j] = t; }
        float inv = 1.0f / a[col][col];
        for (int j = 0; j < 8; j++) a[col][j] *= inv;
        for (int r = 0; r < 4; r++) {
            if (r == col) continue;
            float f = a[r][col];
            for (int j = 0; j < 8; j++) a[r][j] -= f * a[col][j];
        }
    }
    for (int i = 0; i < 4; i++)
        for (int j = 0; j < 4; j++) {
            float s = 0.f;
            for (int k = 0; k < 4; k++) s += a[i][4 + k] * posses[k*4 + j];
            diff[i*4 + j] = s;
        }
}

// ---------------------------------------------------------------- per-m prep (+ class hist)
__global__ void k_prep_m(const float* __restrict__ ssf, const float* __restrict__ scoords,
                         const float* __restrict__ gt, const int* __restrict__ ran_mask,
                         const float* __restrict__ diff,
                         float* __restrict__ al, _Float16* __restrict__ aP,
                         float* __restrict__ updf, int* __restrict__ gtcls,
                         int* __restrict__ cnt) {
    __shared__ int hcnt[OUT];
    const int tt = threadIdx.x;          // 0..63
    if (tt < OUT) hcnt[tt] = 0;
    __syncthreads();
    const int m = blockIdx.x * 32 + (tt >> 1);
    const int h = tt & 1;
    {
        const float4* r4 = (const float4*)(ssf + (size_t)m * C);
        float4 row[12]; float s = 0.f;
        #pragma unroll
        for (int c = 0; c < 12; c++) {
            float4 v = r4[h*12 + c];
            row[c] = v;
            s += v.x*v.x + v.y*v.y + v.z*v.z + v.w*v.w;
        }
        s += __shfl_xor(s, 1, 64);
        float scale = 256.0f / sqrtf(s);
        h8* dst = (h8*)aP;
        #pragma unroll
        for (int qq = 0; qq < 6; qq++) {
            int q = h*6 + qq;
            float4 u = row[2*qq], v = row[2*qq+1];
            float xs[8] = {u.x,u.y,u.z,u.w,v.x,v.y,v.z,v.w};
            h8 hi, lo;
            #pragma unroll
            for (int e = 0; e < 8; e++) {
                float xv = xs[e] * scale;
                _Float16 hh = (_Float16)xv;
                hi[e] = hh;
                lo[e] = (_Float16)(xv - (float)hh);
            }
            dst[tsm24(m, q)]      = hi;
            dst[tsm24(m, 12 + q)] = lo;
        }
        if (h == 0) {
            float x = scoords[m*3], y = scoords[m*3+1], z = scoords[m*3+2];
            #pragma unroll
            for (int j = 0; j < 3; j++)
                al[m*3 + j] = diff[j*4+0]*x + diff[j*4+1]*y + diff[j*4+2]*z + diff[j*4+3];
            int best = 0; float bv = gt[(size_t)m*OUT];
            #pragma unroll
            for (int k = 1; k < OUT; k++) {
                float v = gt[(size_t)m*OUT + k];
                if (v > bv) { bv = v; best = k; }
            }
            gtcls[m] = best;
            bool upd = (best < 9 || m < LG || ran_mask[m] == 1);
            updf[m] = upd ? 1.f : 0.f;
            if (upd) atomicAdd(&hcnt[best], 1);
        }
    }
    __syncthreads();
    if (tt < OUT) atomicAdd(&cnt[tt], hcnt[tt]);
}

// ---------------------------------------------------------------- per-n prep (2 threads/row)
__global__ void k_prep_n(const float* __restrict__ mf, const float* __restrict__ ori,
                         _Float16* __restrict__ bQ, _Float16* __restrict__ mfP,
                         float* __restrict__ nmf2, float4* __restrict__ oriP) {
    const int tt = threadIdx.x;          // 0..63
    const int n = blockIdx.x * 32 + (tt >> 1);
    const int h = tt & 1;
    const float4* r4 = (const float4*)(mf + (size_t)n * C);
    float4 row[12]; float s = 0.f;
    #pragma unroll
    for (int c = 0; c < 12; c++) {
        float4 v = r4[h*12 + c];
        row[c] = v;
        s += v.x*v.x + v.y*v.y + v.z*v.z + v.w*v.w;
    }
    s += __shfl_xor(s, 1, 64);
    if (h == 0) {
        nmf2[n] = s;
        float4 o;
        o.x = ori[n*3]; o.y = ori[n*3+1]; o.z = ori[n*3+2]; o.w = 0.f;
        oriP[n] = o;
    }
    float scn = 256.0f / sqrtf(s);
    h8* dB = (h8*)bQ;
    h8* dF = (h8*)mfP;
    #pragma unroll
    for (int qq = 0; qq < 6; qq++) {
        int q = h*6 + qq;
        float4 u = row[2*qq], v = row[2*qq+1];
        float xs[8] = {u.x,u.y,u.z,u.w,v.x,v.y,v.z,v.w};
        h8 hiN, loN, hiF, loF;
        #pragma unroll
        for (int e = 0; e < 8; e++) {
            float xn = xs[e] * scn;
            _Float16 hn = (_Float16)xn;
            hiN[e] = hn; loN[e] = (_Float16)(xn - (float)hn);
            float xf = xs[e] * 256.0f;
            _Float16 hf = (_Float16)xf;
            hiF[e] = hf; loF[e] = (_Float16)(xf - (float)hf);
        }
        dB[tsm24(n, q)]    = hiN;
        dB[tsm24(n, 12+q)] = loN;
        dF[tsm24(n, q)]    = hiF;
        dF[tsm24(n, 12+q)] = loF;
    }
}

// ---------------------------------------------------------------- pass A: MFMA argmin
// 128m resident; streams 16 tiles of 128n double-buffered. ori side data is
// register-prefetched one tile ahead (off the epilogue critical path).
__global__ __launch_bounds__(512, 1) void k_argmin(
        const _Float16* __restrict__ aP, const _Float16* __restrict__ bQ,
        const float* __restrict__ al, const float4* __restrict__ oriP,
        float* __restrict__ pav, int* __restrict__ pai) {
    __shared__ h8 sA[24*128];          // 48 KB resident
    __shared__ h8 sB[2][24*128];       // 2 x 48 KB streamed (128 n-cols/tile)
    __shared__ float xv[4*128];
    __shared__ int   xi[4*128];
    const int t = threadIdx.x;
    const int wave = t >> 6, lane = t & 63;
    const int col = lane & 15, quad = lane >> 4;
    const int wm = wave >> 2, wn = wave & 3;
    const int m0 = blockIdx.x * 128;
    const int sp = blockIdx.y;

    {   // stage resident A + first streamed tile async
        const h8* gA = (const h8*)aP + (size_t)blockIdx.x * 3072;
        #pragma unroll
        for (int q = 0; q < 6; q++) gl_lds16(gA + q*512 + t, sA + q*512 + t);
        const h8* g = (const h8*)bQ + (size_t)sp * 3072;
        #pragma unroll
        for (int q = 0; q < 6; q++) gl_lds16(g + q*512 + t, sB[0] + q*512 + t);
    }
    float mcx[16], mcy[16], mcz[16];
    #pragma unroll
    for (int e = 0; e < 16; e++) {
        int ml = wm*64 + (e>>2)*16 + quad*4 + (e&3);
        mcx[e] = al[(m0+ml)*3+0]; mcy[e] = al[(m0+ml)*3+1]; mcz[e] = al[(m0+ml)*3+2];
    }
    float best[16]; int bidx[16];
    #pragma unroll
    for (int e = 0; e < 16; e++) { best[e] = 3.4e38f; bidx[e] = 0; }

    float4 curO[2], nxtO[2];
    #pragma unroll
    for (int j = 0; j < 2; j++)
        curO[j] = oriP[sp*128 + wn*32 + j*16 + col];

    __syncthreads();                       // sA + sB[0] visible

    const int NT = (N/128) / NSPA;         // 16 tiles per slice
    int cur = 0;
    f4 acc[4][2];
    for (int u = 0; u < NT; u++) {
        const int tile = sp + u*NSPA;
        const bool has_next = (u + 1 < NT);
        if (has_next) {                    // prefetch next tile into other buffer
            const h8* g = (const h8*)bQ + (size_t)(sp + (u+1)*NSPA) * 3072;
            #pragma unroll
            for (int q = 0; q < 6; q++) gl_lds16(g + q*512 + t, sB[cur^1] + q*512 + t);
            #pragma unroll
            for (int j = 0; j < 2; j++)
                nxtO[j] = oriP[(sp + (u+1)*NSPA)*128 + wn*32 + j*16 + col];
        }
        #pragma unroll
        for (int i = 0; i < 4; i++)
            #pragma unroll
            for (int j = 0; j < 2; j++) acc[i][j] = (f4){0.f,0.f,0.f,0.f};

        const h8* sBc = sB[cur];
        #pragma unroll
        for (int ks = 0; ks < 3; ks++) {
            const int hs = ks*4 + quad;    // hi slot; lo slot = 12+hs
            h8 ah[4], alo[4], bh[2], blo[2];
            #pragma unroll
            for (int i = 0; i < 4; i++) {
                int ml = wm*64 + i*16 + col;
                ah[i]  = sA[hs*128 + ml];
                alo[i] = sA[(12+hs)*128 + ml];
            }
            #pragma unroll
            for (int j = 0; j < 2; j++) {
                int r = wn*32 + j*16 + col;
                bh[j]  = sBc[hs*128 + r];
                blo[j] = sBc[(12+hs)*128 + r];
            }
            #pragma unroll
            for (int i = 0; i < 4; i++)
                #pragma unroll
                for (int j = 0; j < 2; j++) {
                    acc[i][j] = __builtin_amdgcn_mfma_f32_16x16x32_f16(ah[i],  bh[j],  acc[i][j], 0, 0, 0);
                    acc[i][j] = __builtin_amdgcn_mfma_f32_16x16x32_f16(ah[i],  blo[j], acc[i][j], 0, 0, 0);
                    acc[i][j] = __builtin_amdgcn_mfma_f32_16x16x32_f16(alo[i], bh[j],  acc[i][j], 0, 0, 0);
                }
        }
        // epilogue: running per-lane argmin over this tile (side data from regs)
        const int n0t = tile * 128;
        #pragma unroll
        for (int j = 0; j < 2; j++) {
            int n = n0t + wn*32 + j*16 + col;
            float ncx = curO[j].x, ncy = curO[j].y, ncz = curO[j].z;
            #pragma unroll
            for (int e = 0; e < 16; e++) {
                float dot = acc[e>>2][j][e&3] * (1.0f/65536.0f);
                float dx = mcx[e]-ncx, dy = mcy[e]-ncy, dz = mcz[e]-ncz;
                float d2 = dx*dx + dy*dy + dz*dz;
                float sim = 2.0f - dot - __expf(-2.0f*d2);
                if (sim < best[e]) { best[e] = sim; bidx[e] = n; }
            }
        }
        __syncthreads();      // prefetch landed + all waves done reading sB[cur]
        cur ^= 1;
        if (has_next) { curO[0] = nxtO[0]; curO[1] = nxtO[1]; }
    }
    // butterfly over 16 col-lanes, once per block
    #pragma unroll
    for (int e = 0; e < 16; e++) {
        float bv = best[e]; int bi = bidx[e];
        #pragma unroll
        for (int d = 1; d < 16; d <<= 1) {
            float ov = __shfl_xor(bv, d, 64);
            int   oi = __shfl_xor(bi, d, 64);
            if (ov < bv || (ov == bv && oi < bi)) { bv = ov; bi = oi; }
        }
        best[e] = bv; bidx[e] = bi;
    }
    if (col == 0) {
        #pragma unroll
        for (int e = 0; e < 16; e++) {
            int ml = wm*64 + (e>>2)*16 + quad*4 + (e&3);
            xv[wn*128 + ml] = best[e];
            xi[wn*128 + ml] = bidx[e];
        }
    }
    __syncthreads();
    if (t < 128) {   // single writer per (sp, m)
        float bv = xv[t]; int bi = xi[t];
        #pragma unroll
        for (int w = 1; w < 4; w++) {
            float v = xv[w*128 + t]; int i2 = xi[w*128 + t];
            if (v < bv || (v == bv && i2 < bi)) { bv = v; bi = i2; }
        }
        pav[(size_t)sp * M + m0 + t] = bv;
        pai[(size_t)sp * M + m0 + t] = bi;
    }
}

__global__ void k_argmin_reduce(const float* __restrict__ pav, const int* __restrict__ pai,
                                int* __restrict__ smi, float* __restrict__ out_smi) {
    int m = blockIdx.x * 256 + threadIdx.x;
    if (m >= M) return;
    float best = 3.4e38f; int bidx = 0;
    for (int sp = 0; sp < NSPA; sp++) {
        float v = pav[(size_t)sp * M + m];
        int   i = pai[(size_t)sp * M + m];
        if (v < best || (v == best && i < bidx)) { best = v; bidx = i; }
    }
    smi[m] = bidx;
    out_smi[m] = (float)bidx;
}

// ---------------------------------------------------------------- scan + permute (counting sort)
__global__ void k_scan(const int* __restrict__ cnt, int* __restrict__ meta) {
    if (threadIdx.x != 0 || blockIdx.x != 0) return;
    int run = 0;
    for (int k = 0; k < OUT; k++) { meta[2 + k] = run; run += cnt[k]; }
    meta[0] = run;
    meta[1] = (run + 255) / 256;      // macro-tiles of 256
}

__global__ void k_permute(const int* __restrict__ gtcls, const float* __restrict__ updf,
                          int* __restrict__ meta, int* __restrict__ perm) {
    int m = blockIdx.x * 256 + threadIdx.x;
    if (m >= M) return;
    if (updf[m] == 0.f) return;
    int pos = atomicAdd(&meta[2 + gtcls[m]], 1);
    perm[pos] = m;
}

// gather sorted+compacted mid rows: one thread per (row, slot); also packs the
// per-row side data {n2,x,y,z} + cls consumed by k_uw's register prefetch.
__global__ void k_gather_sorted(const int* __restrict__ meta, const int* __restrict__ perm,
                                const int* __restrict__ smi, const int* __restrict__ gtcls,
                                const _Float16* __restrict__ mfP, const float* __restrict__ nmf2,
                                const float* __restrict__ ori,
                                _Float16* __restrict__ midQ,
                                float4* __restrict__ sideQ, int* __restrict__ sideC) {
    int tid = blockIdx.x * 256 + threadIdx.x;
    int rr = tid / 24;
    int q  = tid - rr * 24;
    int mact = meta[0];
    int mpad = meta[1] * 256;
    if (rr >= mpad) return;
    h8* dst = (h8*)midQ;
    if (rr < mact) {
        int m = perm[rr];
        int s = smi[m];
        dst[tsm24(rr, q)] = ((const h8*)mfP)[tsm24(s, q)];
        if (q == 0) {
            float4 sq;
            sq.x = nmf2[s];
            sq.y = ori[s*3+0]; sq.z = ori[s*3+1]; sq.w = ori[s*3+2];
            sideQ[rr] = sq;
            sideC[rr] = gtcls[m];
        }
    } else {
        dst[tsm24(rr, q)] = (h8)(_Float16)0.f;
        if (q == 0) {
            sideQ[rr] = (float4){1e9f, 0.f, 0.f, 0.f};   // w = exp(-5.55e9) == 0
            sideC[rr] = 0;
        }
    }
}

// ---------------------------------------------------------------- pass B: MFMA class-binned sums
// CONTIGUOUS tile slicing per block (classes non-decreasing across tiles) +
// cross-tile register run-length accumulation: no per-tile shfl chains, no
// per-tile atomics; bins touched only on class change (~every other tile).
__global__ __launch_bounds__(512, 1) void k_uw(
        const _Float16* __restrict__ mfP, const _Float16* __restrict__ midQ,
        const float* __restrict__ nmf2, const float* __restrict__ ori,
        const float4* __restrict__ sideQ, const int* __restrict__ sideC,
        const int* __restrict__ meta, float* __restrict__ pb) {
    __shared__ h8 sN[24*128];          // 48 KB resident n-rows
    __shared__ h8 sB[2][24*128];       // 2 x 48 KB streamed mid tiles
    __shared__ float bins[128*21];
    const int t = threadIdx.x;
    const int wave = t >> 6, lane = t & 63;
    const int col = lane & 15, quad = lane >> 4;
    const int wm = wave >> 2, wn = wave & 3;
    const int n0 = blockIdx.x * 128;
    const int sp = blockIdx.y;
    const int nmac2 = meta[1] * 2;     // 128-col tiles
    const int nq  = (nmac2 + NSPB - 1) / NSPB;
    const int mt0 = sp * nq;
    const int mt1 = (mt0 + nq < nmac2) ? (mt0 + nq) : nmac2;

    {   // stage resident n-rows + first streamed tile async
        const h8* gN = (const h8*)mfP + (size_t)blockIdx.x * 3072;
        #pragma unroll
        for (int q = 0; q < 6; q++) gl_lds16(gN + q*512 + t, sN + q*512 + t);
        if (mt0 < mt1) {
            const h8* g = (const h8*)midQ + (size_t)mt0 * 3072;
            #pragma unroll
            for (int q = 0; q < 6; q++) gl_lds16(g + q*512 + t, sB[0] + q*512 + t);
        }
    }
    for (int i = t; i < 128*21; i += 512) bins[i] = 0.f;

    float nn2[16], ncx[16], ncy[16], ncz[16];
    #pragma unroll
    for (int e = 0; e < 16; e++) {
        int nl = wm*64 + (e>>2)*16 + quad*4 + (e&3);
        int n = n0 + nl;
        nn2[e] = nmf2[n];
        ncx[e] = ori[n*3+0]; ncy[e] = ori[n*3+1]; ncz[e] = ori[n*3+2];
    }

    // run-length accumulator state (classes sorted => non-decreasing per lane)
    float ssum[2][16];
    int   scls[2] = {-1, -1};
    #pragma unroll
    for (int j = 0; j < 2; j++)
        #pragma unroll
        for (int e = 0; e < 16; e++) ssum[j][e] = 0.f;

    float4 curQ[2], nxtQ[2];
    int    curC[2], nxtC[2];
    if (mt0 < mt1) {
        #pragma unroll
        for (int j = 0; j < 2; j++) {
            int r = mt0*128 + wn*32 + j*16 + col;
            curQ[j] = sideQ[r];
            curC[j] = sideC[r];
        }
    }

    __syncthreads();                   // sN + sB[0] + bins init visible

    int cur = 0;
    f4 acc[4][2];
    for (int mt = mt0; mt < mt1; mt++) {
        const bool has_next = (mt + 1 < mt1);
        if (has_next) {                // prefetch next tile into other buffer
            const h8* g = (const h8*)midQ + (size_t)(mt + 1) * 3072;
            #pragma unroll
            for (int q = 0; q < 6; q++) gl_lds16(g + q*512 + t, sB[cur^1] + q*512 + t);
            #pragma unroll
            for (int j = 0; j < 2; j++) {
                int r = (mt+1)*128 + wn*32 + j*16 + col;
                nxtQ[j] = sideQ[r];
                nxtC[j] = sideC[r];
            }
        }
        #pragma unroll
        for (int i = 0; i < 4; i++)
            #pragma unroll
            for (int j = 0; j < 2; j++) acc[i][j] = (f4){0.f,0.f,0.f,0.f};

        const h8* sBc = sB[cur];
        #pragma unroll
        for (int ks = 0; ks < 3; ks++) {
            const int hs = ks*4 + quad;
            h8 ah[4], alo[4], bh[2], blo[2];
            #pragma unroll
            for (int i = 0; i < 4; i++) {
                int ml = wm*64 + i*16 + col;
                ah[i]  = sN[hs*128 + ml];
                alo[i] = sN[(12+hs)*128 + ml];
            }
            #pragma unroll
            for (int j = 0; j < 2; j++) {
                int r = wn*32 + j*16 + col;
                bh[j]  = sBc[hs*128 + r];
                blo[j] = sBc[(12+hs)*128 + r];
            }
            #pragma unroll
            for (int i = 0; i < 4; i++)
                #pragma unroll
                for (int j = 0; j < 2; j++) {
                    acc[i][j] = __builtin_amdgcn_mfma_f32_16x16x32_f16(ah[i],  bh[j],  acc[i][j], 0, 0, 0);
                    acc[i][j] = __builtin_amdgcn_mfma_f32_16x16x32_f16(ah[i],  blo[j], acc[i][j], 0, 0, 0);
                    acc[i][j] = __builtin_amdgcn_mfma_f32_16x16x32_f16(alo[i], bh[j],  acc[i][j], 0, 0, 0);
                }
        }
        // epilogue: accumulate into per-lane run-length registers
        #pragma unroll
        for (int j = 0; j < 2; j++) {
            if (curC[j] != scls[j]) {            // class changed: flush (rare)
                if (scls[j] >= 0) {
                    #pragma unroll
                    for (int e = 0; e < 16; e++) {
                        int nl = wm*64 + (e>>2)*16 + quad*4 + (e&3);
                        atomicAdd(&bins[nl*21 + scls[j]], ssum[j][e]);
                        ssum[j][e] = 0.f;
                    }
                }
                scls[j] = curC[j];
            }
            float m2 = curQ[j].x;
            float mx_ = curQ[j].y, my_ = curQ[j].z, mz_ = curQ[j].w;
            #pragma unroll
            for (int e = 0; e < 16; e++) {
                float dot = acc[e>>2][j][e&3] * (1.0f/65536.0f);
                float fd = fmaxf(nn2[e] + m2 - 2.0f*dot, 0.0f);
                float dx = ncx[e]-mx_, dy = ncy[e]-my_, dz = ncz[e]-mz_;
                float dc = dx*dx + dy*dy + dz*dz;
                ssum[j][e] += __expf(-8.0f*dc - (0.5f/0.09f)*fd);
            }
        }
        __syncthreads();          // prefetch landed + all waves done reading sB[cur]
        cur ^= 1;
        if (has_next) {
            curQ[0] = nxtQ[0]; curQ[1] = nxtQ[1];
            curC[0] = nxtC[0]; curC[1] = nxtC[1];
        }
    }
    // final flush of run-length accumulators
    #pragma unroll
    for (int j = 0; j < 2; j++) {
        if (scls[j] >= 0) {
            #pragma unroll
            for (int e = 0; e < 16; e++) {
                int nl = wm*64 + (e>>2)*16 + quad*4 + (e&3);
                atomicAdd(&bins[nl*21 + scls[j]], ssum[j][e]);
            }
        }
    }
    __syncthreads();
    for (int i = t; i < 128*OUT; i += 512) {
        int loc = i / OUT, k = i - loc*OUT;
        pb[((size_t)sp*N + n0 + loc)*OUT + k] = bins[loc*21 + k];
    }
}

__global__ void k_uw_final(const float* __restrict__ pb, const float* __restrict__ svp,
                           float* __restrict__ out_uw, float* __restrict__ out_spu) {
    int n = blockIdx.x * 256 + threadIdx.x;
    if (n >= N) return;
    float s[OUT];
    #pragma unroll
    for (int k = 0; k < OUT; k++) s[k] = 0.f;
    for (int sp = 0; sp < NSPB; sp++) {
        size_t base = ((size_t)sp * N + n) * OUT;
        #pragma unroll
        for (int k = 0; k < OUT; k++) s[k] += pb[base + k];
    }
    float tot = 0.f;
    #pragma unroll
    for (int k = 0; k < OUT; k++) tot += s[k];
    float rden = 1.0f / (tot + 1e-16f);
    float p[OUT]; float mx = -3.4e38f;
    #pragma unroll
    for (int k = 0; k < OUT; k++) { p[k] = svp[(size_t)n*OUT + k]; mx = fmaxf(mx, p[k]); }
    float es = 0.f;
    #pragma unroll
    for (int k = 0; k < OUT; k++) { p[k] = __expf(p[k] - mx); es += p[k]; }
    float res = 1.0f / es;
    #pragma unroll
    for (int k = 0; k < OUT; k++) {
        float uw = s[k] * rden;
        out_uw[(size_t)n*OUT + k] = uw;
        out_spu[(size_t)n*OUT + k] = 0.5f * (p[k] * res) + 0.5f * uw;
    }
}

// ---------------------------------------------------------------- scatter (lg rows, last-wins)
__global__ void k_scatter_pre(const int* __restrict__ smi, const int* __restrict__ gtcls,
                              const float* __restrict__ spu, float* __restrict__ vals,
                              int* __restrict__ pos, int* __restrict__ flags) {
    int i = blockIdx.x * 256 + threadIdx.x;
    if (i >= LG) return;
    int idx = smi[i];
    float v = spu[(size_t)idx*OUT + gtcls[i]];
    vals[i] = v;
    if (v > 0.1f) atomicOr(&flags[0], 1);
    atomicMax(&pos[idx], i);
}

__global__ void k_scatter_apply(const int* __restrict__ smi, const int* __restrict__ gtcls,
                                const float* __restrict__ vals, const int* __restrict__ pos,
                                const int* __restrict__ flags, float* __restrict__ spu) {
    int i = blockIdx.x * 256 + threadIdx.x;
    if (i >= LG) return;
    int idx = smi[i];
    if (pos[idx] != i) return;
    float v = vals[i];
    bool tmp = flags[0] ? (v > 0.1f) : (v > 0.0f);
    if (!tmp) return;
    int cls = gtcls[i];
    #pragma unroll
    for (int k = 0; k < OUT; k++) spu[(size_t)idx*OUT + k] = (k == cls) ? 1.0f : 0.0f;
}

// ---------------------------------------------------------------- trust / finalize
__global__ void k_trust_pre(const float* __restrict__ spu, float* __restrict__ maxv,
                            int* __restrict__ amax, int* __restrict__ flags) {
    int n = blockIdx.x * 256 + threadIdx.x;
    if (n >= N) return;
    float best = spu[(size_t)n*OUT]; int bi = 0;
    #pragma unroll
    for (int k = 1; k < OUT; k++) {
        float v = spu[(size_t)n*OUT + k];
        if (v > best) { best = v; bi = k; }
    }
    maxv[n] = best; amax[n] = bi;
    if (best >= 0.9f) atomicOr(&flags[1], 1);
}

__global__ void k_finalize(const float* __restrict__ mf, const float* __restrict__ ori,
                           const float* __restrict__ maxv, const int* __restrict__ amax,
                           const int* __restrict__ flags,
                           float* __restrict__ out_trust, float* __restrict__ out_mf,
                           float* __restrict__ out_ori, float* __restrict__ out_pre) {
    int n = blockIdx.x * 256 + threadIdx.x;
    if (n >= N) return;
    float mv = maxv[n];
    bool tr = flags[1] ? (mv >= 0.9f) : (mv >= 0.85f);
    float m = tr ? 1.f : 0.f;
    out_trust[n] = m;
    const float4* src = (const float4*)(mf + (size_t)n * C);
    float4* dst = (float4*)(out_mf + (size_t)n * C);
    #pragma unroll
    for (int c = 0; c < 24; c++) {
        float4 v = src[c];
        v.x *= m; v.y *= m; v.z *= m; v.w *= m;
        dst[c] = v;
    }
    out_ori[n*3]   = ori[n*3]   * m;
    out_ori[n*3+1] = ori[n*3+1] * m;
    out_ori[n*3+2] = ori[n*3+2] * m;
    int bi = amax[n];
    #pragma unroll
    for (int k = 0; k < OUT; k++) out_pre[(size_t)n*OUT + k] = (k == bi) ? m : 0.f;
}

// ---------------------------------------------------------------- launch
extern "C" void kernel_launch(void* const* d_in, const int* in_sizes, int n_in,
                              void* d_out, int out_size, void* d_ws, size_t ws_size,
                              hipStream_t stream) {
    (void)in_sizes; (void)n_in; (void)out_size; (void)ws_size;
    const float* ssf     = (const float*)d_in[0];
    const float* scoords = (const float*)d_in[1];
    const float* gt      = (const float*)d_in[2];
    const float* svp     = (const float*)d_in[3];
    const float* mf      = (const float*)d_in[4];
    const float* ori     = (const float*)d_in[5];
    const float* posses  = (const float*)d_in[6];
    const int*   ran     = (const int*)d_in[7];

    float* out = (float*)d_out;
    float* out_trust = out;
    float* out_mf    = out_trust + N;
    float* out_ori   = out_mf + (size_t)N*C;
    float* out_pre   = out_ori + (size_t)N*3;
    float* out_uw    = out_pre + (size_t)N*OUT;
    float* out_spu   = out_uw  + (size_t)N*OUT;
    float* out_smi   = out_spu + (size_t)N*OUT;

    char* ws = (char*)d_ws;
    float*     w_diff  = (float*)(ws + OFF_DIFF);
    float*     w_al    = (float*)(ws + OFF_AL);
    float*     w_nmf2  = (float*)(ws + OFF_NMF2);
    float*     w_updf  = (float*)(ws + OFF_UPDF);
    int*       w_gtc   = (int*)(ws + OFF_GTC);
    int*       w_smi   = (int*)(ws + OFF_SMI);
    int*       w_perm  = (int*)(ws + OFF_PERM);
    _Float16*  w_aP    = (_Float16*)(ws + OFF_AP);
    _Float16*  w_bQ    = (_Float16*)(ws + OFF_BQ);
    _Float16*  w_mfP   = (_Float16*)(ws + OFF_MFP);
    _Float16*  w_midQ  = (_Float16*)(ws + OFF_MIDQ);
    float*     w_pav   = (float*)(ws + OFF_PAV);
    int*       w_pai   = (int*)(ws + OFF_PAI);
    float*     w_pb    = (float*)(ws + OFF_PB);
    float*     w_vals  = (float*)(ws + OFF_VALS);
    int*       w_pos   = (int*)(ws + OFF_POS);
    float*     w_maxv  = (float*)(ws + OFF_MAXV);
    int*       w_amax  = (int*)(ws + OFF_AMAX);
    int*       w_flags = (int*)(ws + OFF_FLAGS);
    int*       w_cnt   = (int*)(ws + OFF_CNT);
    int*       w_meta  = (int*)(ws + OFF_META);
    float4*    w_oriP  = (float4*)(ws + OFF_ORIP);
    float4*    w_sideQ = (float4*)(ws + OFF_SIDEQ);
    int*       w_sideC = (int*)(ws + OFF_SIDEC);

    hipMemsetAsync(w_pos, 0xFF, (size_t)N*4, stream);   // -1
    hipMemsetAsync(w_flags, 0, 8, stream);
    hipMemsetAsync(w_cnt, 0, OUT*4, stream);

    k_diff<<<1, 64, 0, stream>>>(posses, w_diff);
    k_prep_m<<<M/32, 64, 0, stream>>>(ssf, scoords, gt, ran, w_diff,
                                      w_al, w_aP, w_updf, w_gtc, w_cnt);
    k_prep_n<<<N/32, 64, 0, stream>>>(mf, ori, w_bQ, w_mfP, w_nmf2, w_oriP);
    k_argmin<<<dim3(M/128, NSPA), 512, 0, stream>>>(w_aP, w_bQ, w_al, w_oriP, w_pav, w_pai);
    k_argmin_reduce<<<M/256, 256, 0, stream>>>(w_pav, w_pai, w_smi, out_smi);
    k_scan<<<1, 64, 0, stream>>>(w_cnt, w_meta);
    k_permute<<<M/256, 256, 0, stream>>>(w_gtc, w_updf, w_meta, w_perm);
    k_gather_sorted<<<((M+256)*24)/256, 256, 0, stream>>>(w_meta, w_perm, w_smi, w_gtc,
                                                          w_mfP, w_nmf2, ori,
                                                          w_midQ, w_sideQ, w_sideC);
    k_uw<<<dim3(N/128, NSPB), 512, 0, stream>>>(w_mfP, w_midQ, w_nmf2, ori,
                                                w_sideQ, w_sideC, w_meta, w_pb);
    k_uw_final<<<N/256, 256, 0, stream>>>(w_pb, svp, out_uw, out_spu);
    k_scatter_pre<<<LG/256, 256, 0, stream>>>(w_smi, w_gtc, out_spu, w_vals, w_pos, w_flags);
    k_scatter_apply<<<LG/256, 256, 0, stream>>>(w_smi, w_gtc, w_vals, w_pos, w_flags, out_spu);
    k_trust_pre<<<N/256, 256, 0, stream>>>(out_spu, w_maxv, w_amax, w_flags);
    k_finalize<<<N/256, 256, 0, stream>>>(mf, ori, w_maxv, w_amax, w_flags,
                                          out_trust, out_mf, out_ori, out_pre);
}

// Round 3
// 272.429 us; speedup vs baseline: 1.8116x; 1.8116x over previous
//
#include <hip/hip_runtime.h>
#include <math.h>

#define N 8192
#define M 8192
#define C 96
#define OUT 20
#define LG 2048

#define KP2 192     // stored K per row: [hi(96)|lo(96)] fp16, 24 h8 slots
#define NSPA 4      // y-slices pass A (256 blocks = 1/CU)
#define NSPB 4      // y-slices pass B (256 blocks = 1/CU)

typedef _Float16 h8 __attribute__((ext_vector_type(8)));
typedef float    f4 __attribute__((ext_vector_type(4)));

// async global->LDS, 16B per lane, no VGPR round-trip (m97 path)
__device__ __forceinline__ void gl_lds16(const h8* g, h8* l) {
    __builtin_amdgcn_global_load_lds(
        (const __attribute__((address_space(1))) unsigned int*)g,
        (__attribute__((address_space(3))) unsigned int*)l,
        16, 0, 0);
}

// tile-slot-major h8 index: rows grouped in 128-row tiles, slot-major inside
__device__ __forceinline__ size_t tsm24(int row, int slot) {
    return ((size_t)(row >> 7) * 24 + slot) * 128 + (row & 127);
}

// ---------------- workspace layout (bytes, all 256-aligned) ----------------
constexpr size_t OFF_DIFF  = 0;
constexpr size_t OFF_AL    = 256;
constexpr size_t OFF_NMF2  = OFF_AL    + (size_t)M*3*4;
constexpr size_t OFF_UPDF  = OFF_NMF2  + (size_t)N*4;
constexpr size_t OFF_GTC   = OFF_UPDF  + (size_t)M*4;
constexpr size_t OFF_SMI   = OFF_GTC   + (size_t)M*4;
constexpr size_t OFF_PERM  = OFF_SMI   + (size_t)M*4;
constexpr size_t OFF_AP    = OFF_PERM  + (size_t)M*4;            // M x 192 fp16 (tsm24)
constexpr size_t OFF_BQ    = OFF_AP    + (size_t)M*KP2*2;        // N x 192 fp16
constexpr size_t OFF_MFP   = OFF_BQ    + (size_t)N*KP2*2;        // N x 192 fp16
constexpr size_t OFF_MIDQ  = OFF_MFP   + (size_t)N*KP2*2;        // (M+256) x 192 fp16
constexpr size_t OFF_MIDN2 = OFF_MIDQ  + (size_t)(M+256)*KP2*2;
constexpr size_t OFF_MIDC  = OFF_MIDN2 + (size_t)(M+256)*4;
constexpr size_t OFF_CLS   = OFF_MIDC  + (size_t)(M+256)*3*4;
constexpr size_t OFF_PAV   = OFF_CLS   + (size_t)(M+256)*4;      // NSPA x M
constexpr size_t OFF_PAI   = OFF_PAV   + (size_t)NSPA*M*4;
constexpr size_t OFF_PB    = OFF_PAI   + (size_t)NSPA*M*4;       // NSPB x N x 20
constexpr size_t OFF_VALS  = OFF_PB    + (size_t)NSPB*N*OUT*4;
constexpr size_t OFF_POS   = OFF_VALS  + (size_t)LG*4;
constexpr size_t OFF_MAXV  = OFF_POS   + (size_t)N*4;
constexpr size_t OFF_AMAX  = OFF_MAXV  + (size_t)N*4;
constexpr size_t OFF_FLAGS = OFF_AMAX  + (size_t)N*4;
constexpr size_t OFF_CNT   = OFF_FLAGS + 256;
constexpr size_t OFF_META  = OFF_CNT   + 256;   // [0]=Mact [1]=nmacro [2..21]=cursor

// ---------------------------------------------------------------- 4x4 inverse
__global__ void k_diff(const float* __restrict__ posses, float* __restrict__ diff) {
    if (threadIdx.x != 0 || blockIdx.x != 0) return;
    float a[4][8];
    for (int i = 0; i < 4; i++)
        for (int j = 0; j < 4; j++) {
            a[i][j]     = posses[16 + i*4 + j];
            a[i][4 + j] = (i == j) ? 1.f : 0.f;
        }
    for (int col = 0; col < 4; col++) {
        int piv = col; float mx = fabsf(a[col][col]);
        for (int r = col + 1; r < 4; r++) {
            float v = fabsf(a[r][col]);
            if (v > mx) { mx = v; piv = r; }
        }
        if (piv != col)
            for (int j = 0; j < 8; j++) { float t = a[col][j]; a[col][j] = a[piv][j]; a[piv][j] = t; }
        float inv = 1.0f / a[col][col];
        for (int j = 0; j < 8; j++) a[col][j] *= inv;
        for (int r = 0; r < 4; r++) {
            if (r == col) continue;
            float f = a[r][col];
            for (int j = 0; j < 8; j++) a[r][j] -= f * a[col][j];
        }
    }
    for (int i = 0; i < 4; i++)
        for (int j = 0; j < 4; j++) {
            float s = 0.f;
            for (int k = 0; k < 4; k++) s += a[i][4 + k] * posses[k*4 + j];
            diff[i*4 + j] = s;
        }
}

// ---------------------------------------------------------------- per-m prep (+ class hist)
// 256 blocks x 64 threads (2 threads/row, 32 rows/block).
__global__ void k_prep_m(const float* __restrict__ ssf, const float* __restrict__ scoords,
                         const float* __restrict__ gt, const int* __restrict__ ran_mask,
                         const float* __restrict__ diff,
                         float* __restrict__ al, _Float16* __restrict__ aP,
                         float* __restrict__ updf, int* __restrict__ gtcls,
                         int* __restrict__ cnt) {
    __shared__ int hcnt[OUT];
    const int tt = threadIdx.x;          // 0..63
    if (tt < OUT) hcnt[tt] = 0;
    __syncthreads();
    const int m = blockIdx.x * 32 + (tt >> 1);
    const int h = tt & 1;
    {
        const float4* r4 = (const float4*)(ssf + (size_t)m * C);
        float4 row[12]; float s = 0.f;
        #pragma unroll
        for (int c = 0; c < 12; c++) {
            float4 v = r4[h*12 + c];
            row[c] = v;
            s += v.x*v.x + v.y*v.y + v.z*v.z + v.w*v.w;
        }
        s += __shfl_xor(s, 1, 64);
        float scale = 256.0f / sqrtf(s);
        h8* dst = (h8*)aP;
        #pragma unroll
        for (int qq = 0; qq < 6; qq++) {
            int q = h*6 + qq;
            float4 u = row[2*qq], v = row[2*qq+1];
            float xs[8] = {u.x,u.y,u.z,u.w,v.x,v.y,v.z,v.w};
            h8 hi, lo;
            #pragma unroll
            for (int e = 0; e < 8; e++) {
                float xv = xs[e] * scale;
                _Float16 hh = (_Float16)xv;
                hi[e] = hh;
                lo[e] = (_Float16)(xv - (float)hh);
            }
            dst[tsm24(m, q)]      = hi;
            dst[tsm24(m, 12 + q)] = lo;
        }
        if (h == 0) {
            float x = scoords[m*3], y = scoords[m*3+1], z = scoords[m*3+2];
            #pragma unroll
            for (int j = 0; j < 3; j++)
                al[m*3 + j] = diff[j*4+0]*x + diff[j*4+1]*y + diff[j*4+2]*z + diff[j*4+3];
            int best = 0; float bv = gt[(size_t)m*OUT];
            #pragma unroll
            for (int k = 1; k < OUT; k++) {
                float v = gt[(size_t)m*OUT + k];
                if (v > bv) { bv = v; best = k; }
            }
            gtcls[m] = best;
            bool upd = (best < 9 || m < LG || ran_mask[m] == 1);
            updf[m] = upd ? 1.f : 0.f;
            if (upd) atomicAdd(&hcnt[best], 1);
        }
    }
    __syncthreads();
    if (tt < OUT) atomicAdd(&cnt[tt], hcnt[tt]);
}

// ---------------------------------------------------------------- per-n prep (2 threads/row)
__global__ void k_prep_n(const float* __restrict__ mf, _Float16* __restrict__ bQ,
                         _Float16* __restrict__ mfP, float* __restrict__ nmf2) {
    const int tt = threadIdx.x;          // 0..63
    const int n = blockIdx.x * 32 + (tt >> 1);
    const int h = tt & 1;
    const float4* r4 = (const float4*)(mf + (size_t)n * C);
    float4 row[12]; float s = 0.f;
    #pragma unroll
    for (int c = 0; c < 12; c++) {
        float4 v = r4[h*12 + c];
        row[c] = v;
        s += v.x*v.x + v.y*v.y + v.z*v.z + v.w*v.w;
    }
    s += __shfl_xor(s, 1, 64);
    if (h == 0) nmf2[n] = s;
    float scn = 256.0f / sqrtf(s);
    h8* dB = (h8*)bQ;
    h8* dF = (h8*)mfP;
    #pragma unroll
    for (int qq = 0; qq < 6; qq++) {
        int q = h*6 + qq;
        float4 u = row[2*qq], v = row[2*qq+1];
        float xs[8] = {u.x,u.y,u.z,u.w,v.x,v.y,v.z,v.w};
        h8 hiN, loN, hiF, loF;
        #pragma unroll
        for (int e = 0; e < 8; e++) {
            float xn = xs[e] * scn;
            _Float16 hn = (_Float16)xn;
            hiN[e] = hn; loN[e] = (_Float16)(xn - (float)hn);
            float xf = xs[e] * 256.0f;
            _Float16 hf = (_Float16)xf;
            hiF[e] = hf; loF[e] = (_Float16)(xf - (float)hf);
        }
        dB[tsm24(n, q)]    = hiN;
        dB[tsm24(n, 12+q)] = loN;
        dF[tsm24(n, q)]    = hiF;
        dF[tsm24(n, 12+q)] = loF;
    }
}

// ---------------------------------------------------------------- pass A: MFMA argmin
// 1024 threads = 16 waves (4 waves/SIMD for latency hiding). 128m resident,
// streams 8 macro-tiles of 256n (round-0 proven structure, more TLP).
// Wave grid 4m x 4n: wave tile 32m x 64n, acc[2][4].
__global__ __launch_bounds__(1024, 4) void k_argmin(
        const _Float16* __restrict__ aP, const _Float16* __restrict__ bQ,
        const float* __restrict__ al, const float* __restrict__ ori,
        float* __restrict__ pav, int* __restrict__ pai) {
    __shared__ h8 sA[24*128];          // 48 KB resident full-K
    __shared__ h8 sB[2*24*128];        // 96 KB (256 n-cols = 2 row-tiles)
    __shared__ float xv[4*128];
    __shared__ int   xi[4*128];
    const int t = threadIdx.x;
    const int wave = t >> 6, lane = t & 63;
    const int col = lane & 15, quad = lane >> 4;
    const int wm = wave >> 2, wn = wave & 3;     // 4m x 4n
    const int m0 = blockIdx.x * 128;
    const int sp = blockIdx.y;

    {   // stage resident A async (3 x 16B per thread)
        const h8* gA = (const h8*)aP + (size_t)blockIdx.x * 3072;
        #pragma unroll
        for (int q = 0; q < 3; q++) gl_lds16(gA + q*1024 + t, sA + q*1024 + t);
    }
    float mcx[8], mcy[8], mcz[8];
    #pragma unroll
    for (int e = 0; e < 8; e++) {
        int ml = wm*32 + (e>>2)*16 + quad*4 + (e&3);
        mcx[e] = al[(m0+ml)*3+0]; mcy[e] = al[(m0+ml)*3+1]; mcz[e] = al[(m0+ml)*3+2];
    }
    float best[8]; int bidx[8];
    #pragma unroll
    for (int e = 0; e < 8; e++) { best[e] = 3.4e38f; bidx[e] = 0; }

    const h8* gB = (const h8*)bQ;
    f4 acc[2][4];
    for (int u = 0; u < 32/NSPA; u++) {
        const int tile = sp + u*NSPA;
        __syncthreads();                       // prev compute done reading sB
        {
            const h8* g = gB + (size_t)(2*tile) * 3072;
            #pragma unroll
            for (int q = 0; q < 6; q++) gl_lds16(g + q*1024 + t, sB + q*1024 + t);
        }
        __syncthreads();                       // drains vmcnt -> sA/sB visible
        #pragma unroll
        for (int i = 0; i < 2; i++)
            #pragma unroll
            for (int j = 0; j < 4; j++) acc[i][j] = (f4){0.f,0.f,0.f,0.f};

        #pragma unroll
        for (int ks = 0; ks < 3; ks++) {
            const int hs = ks*4 + quad;        // hi slot; lo slot = 12+hs
            h8 ah[2], alo[2], bh[4], blo[4];
            #pragma unroll
            for (int i = 0; i < 2; i++) {
                int ml = wm*32 + i*16 + col;
                ah[i]  = sA[hs*128 + ml];
                alo[i] = sA[(12+hs)*128 + ml];
            }
            #pragma unroll
            for (int j = 0; j < 4; j++) {
                int r = wn*64 + j*16 + col;
                int tb = (r >> 7) * 3072, rl = r & 127;
                bh[j]  = sB[tb + hs*128 + rl];
                blo[j] = sB[tb + (12+hs)*128 + rl];
            }
            #pragma unroll
            for (int i = 0; i < 2; i++)
                #pragma unroll
                for (int j = 0; j < 4; j++) {
                    acc[i][j] = __builtin_amdgcn_mfma_f32_16x16x32_f16(ah[i],  bh[j],  acc[i][j], 0, 0, 0);
                    acc[i][j] = __builtin_amdgcn_mfma_f32_16x16x32_f16(ah[i],  blo[j], acc[i][j], 0, 0, 0);
                    acc[i][j] = __builtin_amdgcn_mfma_f32_16x16x32_f16(alo[i], bh[j],  acc[i][j], 0, 0, 0);
                }
        }
        // epilogue: running per-lane argmin over this macro-tile
        const int n0t = tile * 256;
        #pragma unroll
        for (int j = 0; j < 4; j++) {
            int n = n0t + wn*64 + j*16 + col;
            float ncx = ori[n*3+0], ncy = ori[n*3+1], ncz = ori[n*3+2];
            #pragma unroll
            for (int e = 0; e < 8; e++) {
                float dot = acc[e>>2][j][e&3] * (1.0f/65536.0f);
                float dx = mcx[e]-ncx, dy = mcy[e]-ncy, dz = mcz[e]-ncz;
                float d2 = dx*dx + dy*dy + dz*dz;
                float sim = 2.0f - dot - __expf(-2.0f*d2);
                if (sim < best[e]) { best[e] = sim; bidx[e] = n; }
            }
        }
    }
    // butterfly over 16 col-lanes, once per block
    #pragma unroll
    for (int e = 0; e < 8; e++) {
        float bv = best[e]; int bi = bidx[e];
        #pragma unroll
        for (int d = 1; d < 16; d <<= 1) {
            float ov = __shfl_xor(bv, d, 64);
            int   oi = __shfl_xor(bi, d, 64);
            if (ov < bv || (ov == bv && oi < bi)) { bv = ov; bi = oi; }
        }
        best[e] = bv; bidx[e] = bi;
    }
    if (col == 0) {
        #pragma unroll
        for (int e = 0; e < 8; e++) {
            int ml = wm*32 + (e>>2)*16 + quad*4 + (e&3);
            xv[wn*128 + ml] = best[e];
            xi[wn*128 + ml] = bidx[e];
        }
    }
    __syncthreads();
    if (t < 128) {   // single writer per (sp, m)
        float bv = xv[t]; int bi = xi[t];
        #pragma unroll
        for (int w = 1; w < 4; w++) {
            float v = xv[w*128 + t]; int i2 = xi[w*128 + t];
            if (v < bv || (v == bv && i2 < bi)) { bv = v; bi = i2; }
        }
        pav[(size_t)sp * M + m0 + t] = bv;
        pai[(size_t)sp * M + m0 + t] = bi;
    }
}

__global__ void k_argmin_reduce(const float* __restrict__ pav, const int* __restrict__ pai,
                                int* __restrict__ smi, float* __restrict__ out_smi) {
    int m = blockIdx.x * 256 + threadIdx.x;
    if (m >= M) return;
    float best = 3.4e38f; int bidx = 0;
    for (int sp = 0; sp < NSPA; sp++) {
        float v = pav[(size_t)sp * M + m];
        int   i = pai[(size_t)sp * M + m];
        if (v < best || (v == best && i < bidx)) { best = v; bidx = i; }
    }
    smi[m] = bidx;
    out_smi[m] = (float)bidx;
}

// ---------------------------------------------------------------- scan + permute (counting sort)
__global__ void k_scan(const int* __restrict__ cnt, int* __restrict__ meta) {
    if (threadIdx.x != 0 || blockIdx.x != 0) return;
    int run = 0;
    for (int k = 0; k < OUT; k++) { meta[2 + k] = run; run += cnt[k]; }
    meta[0] = run;
    meta[1] = (run + 255) / 256;      // macro-tiles of 256
}

__global__ void k_permute(const int* __restrict__ gtcls, const float* __restrict__ updf,
                          int* __restrict__ meta, int* __restrict__ perm) {
    int m = blockIdx.x * 256 + threadIdx.x;
    if (m >= M) return;
    if (updf[m] == 0.f) return;
    int pos = atomicAdd(&meta[2 + gtcls[m]], 1);
    perm[pos] = m;
}

// gather sorted+compacted mid rows: one thread per (row, slot)
__global__ void k_gather_sorted(const int* __restrict__ meta, const int* __restrict__ perm,
                                const int* __restrict__ smi, const int* __restrict__ gtcls,
                                const _Float16* __restrict__ mfP, const float* __restrict__ nmf2,
                                const float* __restrict__ ori,
                                _Float16* __restrict__ midQ, float* __restrict__ midn2,
                                float* __restrict__ midc, int* __restrict__ cls_s) {
    int tid = blockIdx.x * 256 + threadIdx.x;
    int rr = tid / 24;
    int q  = tid - rr * 24;
    int mact = meta[0];
    int mpad = meta[1] * 256;
    if (rr >= mpad) return;
    h8* dst = (h8*)midQ;
    if (rr < mact) {
        int m = perm[rr];
        int s = smi[m];
        dst[tsm24(rr, q)] = ((const h8*)mfP)[tsm24(s, q)];
        if (q == 0) {
            midn2[rr] = nmf2[s];
            midc[rr*3+0] = ori[s*3+0];
            midc[rr*3+1] = ori[s*3+1];
            midc[rr*3+2] = ori[s*3+2];
            cls_s[rr] = gtcls[m];
        }
    } else {
        dst[tsm24(rr, q)] = (h8)(_Float16)0.f;
        if (q == 0) {
            midn2[rr] = 1e9f;     // w = exp(-5.55e9) == 0 exactly
            midc[rr*3+0] = 0.f; midc[rr*3+1] = 0.f; midc[rr*3+2] = 0.f;
            cls_s[rr] = 0;
        }
    }
}

// ---------------------------------------------------------------- pass B: MFMA class-binned sums
// 1024 threads = 16 waves (4/SIMD). Round-0 proven structure: single-buffered
// 256-col mid tiles (strided sp), shfl+atomic epilogue with uniform-class fast path.
__global__ __launch_bounds__(1024, 4) void k_uw(
        const _Float16* __restrict__ mfP, const _Float16* __restrict__ midQ,
        const float* __restrict__ nmf2, const float* __restrict__ ori,
        const float* __restrict__ midn2, const float* __restrict__ midc,
        const int* __restrict__ cls_s, const int* __restrict__ meta,
        float* __restrict__ pb) {
    __shared__ h8 sN[24*128];          // 48 KB resident n-rows
    __shared__ h8 sB[2*24*128];        // 96 KB streamed mid macro-tile
    __shared__ float bins[128*21];
    const int t = threadIdx.x;
    const int wave = t >> 6, lane = t & 63;
    const int col = lane & 15, quad = lane >> 4;
    const int wm = wave >> 2, wn = wave & 3;     // 4m x 4n
    const int n0 = blockIdx.x * 128;
    const int sp = blockIdx.y;
    const int nmac = meta[1];

    {   // stage resident n-rows async
        const h8* gN = (const h8*)mfP + (size_t)blockIdx.x * 3072;
        #pragma unroll
        for (int q = 0; q < 3; q++) gl_lds16(gN + q*1024 + t, sN + q*1024 + t);
    }
    for (int i = t; i < 128*21; i += 1024) bins[i] = 0.f;

    float nn2[8], ncx[8], ncy[8], ncz[8];
    #pragma unroll
    for (int e = 0; e < 8; e++) {
        int nl = wm*32 + (e>>2)*16 + quad*4 + (e&3);
        int n = n0 + nl;
        nn2[e] = nmf2[n];
        ncx[e] = ori[n*3+0]; ncy[e] = ori[n*3+1]; ncz[e] = ori[n*3+2];
    }

    const h8* gB = (const h8*)midQ;
    f4 acc[2][4];
    for (int mt = sp; mt < nmac; mt += NSPB) {
        const int mb = mt * 256;
        __syncthreads();
        {
            const h8* g = gB + (size_t)(2*mt) * 3072;
            #pragma unroll
            for (int q = 0; q < 6; q++) gl_lds16(g + q*1024 + t, sB + q*1024 + t);
        }
        __syncthreads();
        #pragma unroll
        for (int i = 0; i < 2; i++)
            #pragma unroll
            for (int j = 0; j < 4; j++) acc[i][j] = (f4){0.f,0.f,0.f,0.f};

        #pragma unroll
        for (int ks = 0; ks < 3; ks++) {
            const int hs = ks*4 + quad;
            h8 ah[2], alo[2], bh[4], blo[4];
            #pragma unroll
            for (int i = 0; i < 2; i++) {
                int ml = wm*32 + i*16 + col;
                ah[i]  = sN[hs*128 + ml];
                alo[i] = sN[(12+hs)*128 + ml];
            }
            #pragma unroll
            for (int j = 0; j < 4; j++) {
                int r = wn*64 + j*16 + col;
                int tb = (r >> 7) * 3072, rl = r & 127;
                bh[j]  = sB[tb + hs*128 + rl];
                blo[j] = sB[tb + (12+hs)*128 + rl];
            }
            #pragma unroll
            for (int i = 0; i < 2; i++)
                #pragma unroll
                for (int j = 0; j < 4; j++) {
                    acc[i][j] = __builtin_amdgcn_mfma_f32_16x16x32_f16(ah[i],  bh[j],  acc[i][j], 0, 0, 0);
                    acc[i][j] = __builtin_amdgcn_mfma_f32_16x16x32_f16(ah[i],  blo[j], acc[i][j], 0, 0, 0);
                    acc[i][j] = __builtin_amdgcn_mfma_f32_16x16x32_f16(alo[i], bh[j],  acc[i][j], 0, 0, 0);
                }
        }
        // epilogue: fold into class bins (LDS)
        {
            int mm[4]; float m2[4], mx_[4], my_[4], mz_[4]; int pc[4];
            #pragma unroll
            for (int j = 0; j < 4; j++) {
                mm[j] = mb + wn*64 + j*16 + col;
                m2[j] = midn2[mm[j]];
                mx_[j] = midc[mm[j]*3+0]; my_[j] = midc[mm[j]*3+1]; mz_[j] = midc[mm[j]*3+2];
                pc[j] = cls_s[mm[j]];
            }
            int seg0 = cls_s[mb + wn*64];
            int seg1 = cls_s[mb + wn*64 + 63];
            if (seg0 == seg1) {   // wave's 64 cols uniform class
                #pragma unroll
                for (int e = 0; e < 8; e++) {
                    float rs = 0.f;
                    #pragma unroll
                    for (int j = 0; j < 4; j++) {
                        float dot = acc[e>>2][j][e&3] * (1.0f/65536.0f);
                        float fd = fmaxf(nn2[e] + m2[j] - 2.0f*dot, 0.0f);
                        float dx = ncx[e]-mx_[j], dy = ncy[e]-my_[j], dz = ncz[e]-mz_[j];
                        float dc = dx*dx + dy*dy + dz*dz;
                        rs += __expf(-8.0f*dc - (0.5f/0.09f)*fd);
                    }
                    rs += __shfl_xor(rs, 1, 64);
                    rs += __shfl_xor(rs, 2, 64);
                    rs += __shfl_xor(rs, 4, 64);
                    rs += __shfl_xor(rs, 8, 64);
                    if (col == 0) {
                        int nl = wm*32 + (e>>2)*16 + quad*4 + (e&3);
                        atomicAdd(&bins[nl*21 + seg0], rs);
                    }
                }
            } else {              // boundary segment: per-lane run-length into LDS
                #pragma unroll
                for (int e = 0; e < 8; e++) {
                    int nl = wm*32 + (e>>2)*16 + quad*4 + (e&3);
                    float cur = 0.f; int cc = -1;
                    #pragma unroll
                    for (int j = 0; j < 4; j++) {
                        float dot = acc[e>>2][j][e&3] * (1.0f/65536.0f);
                        float fd = fmaxf(nn2[e] + m2[j] - 2.0f*dot, 0.0f);
                        float dx = ncx[e]-mx_[j], dy = ncy[e]-my_[j], dz = ncz[e]-mz_[j];
                        float dc = dx*dx + dy*dy + dz*dz;
                        float w = __expf(-8.0f*dc - (0.5f/0.09f)*fd);
                        if (pc[j] != cc) {
                            if (cc >= 0) atomicAdd(&bins[nl*21 + cc], cur);
                            cc = pc[j]; cur = 0.f;
                        }
                        cur += w;
                    }
                    if (cc >= 0) atomicAdd(&bins[nl*21 + cc], cur);
                }
            }
        }
    }
    __syncthreads();
    for (int i = t; i < 128*OUT; i += 1024) {
        int loc = i / OUT, k = i - loc*OUT;
        pb[((size_t)sp*N + n0 + loc)*OUT + k] = bins[loc*21 + k];
    }
}

__global__ void k_uw_final(const float* __restrict__ pb, const float* __restrict__ svp,
                           float* __restrict__ out_uw, float* __restrict__ out_spu) {
    int n = blockIdx.x * 256 + threadIdx.x;
    if (n >= N) return;
    float s[OUT];
    #pragma unroll
    for (int k = 0; k < OUT; k++) s[k] = 0.f;
    for (int sp = 0; sp < NSPB; sp++) {
        size_t base = ((size_t)sp * N + n) * OUT;
        #pragma unroll
        for (int k = 0; k < OUT; k++) s[k] += pb[base + k];
    }
    float tot = 0.f;
    #pragma unroll
    for (int k = 0; k < OUT; k++) tot += s[k];
    float rden = 1.0f / (tot + 1e-16f);
    float p[OUT]; float mx = -3.4e38f;
    #pragma unroll
    for (int k = 0; k < OUT; k++) { p[k] = svp[(size_t)n*OUT + k]; mx = fmaxf(mx, p[k]); }
    float es = 0.f;
    #pragma unroll
    for (int k = 0; k < OUT; k++) { p[k] = __expf(p[k] - mx); es += p[k]; }
    float res = 1.0f / es;
    #pragma unroll
    for (int k = 0; k < OUT; k++) {
        float uw = s[k] * rden;
        out_uw[(size_t)n*OUT + k] = uw;
        out_spu[(size_t)n*OUT + k] = 0.5f * (p[k] * res) + 0.5f * uw;
    }
}

// ---------------------------------------------------------------- scatter (lg rows, last-wins)
__global__ void k_scatter_pre(const int* __restrict__ smi, const int* __restrict__ gtcls,
                              const float* __restrict__ spu, float* __restrict__ vals,
                              int* __restrict__ pos, int* __restrict__ flags) {
    int i = blockIdx.x * 256 + threadIdx.x;
    if (i >= LG) return;
    int idx = smi[i];
    float v = spu[(size_t)idx*OUT + gtcls[i]];
    vals[i] = v;
    if (v > 0.1f) atomicOr(&flags[0], 1);
    atomicMax(&pos[idx], i);
}

__global__ void k_scatter_apply(const int* __restrict__ smi, const int* __restrict__ gtcls,
                                const float* __restrict__ vals, const int* __restrict__ pos,
                                const int* __restrict__ flags, float* __restrict__ spu) {
    int i = blockIdx.x * 256 + threadIdx.x;
    if (i >= LG) return;
    int idx = smi[i];
    if (pos[idx] != i) return;
    float v = vals[i];
    bool tmp = flags[0] ? (v > 0.1f) : (v > 0.0f);
    if (!tmp) return;
    int cls = gtcls[i];
    #pragma unroll
    for (int k = 0; k < OUT; k++) spu[(size_t)idx*OUT + k] = (k == cls) ? 1.0f : 0.0f;
}

// ---------------------------------------------------------------- trust / finalize
__global__ void k_trust_pre(const float* __restrict__ spu, float* __restrict__ maxv,
                            int* __restrict__ amax, int* __restrict__ flags) {
    int n = blockIdx.x * 256 + threadIdx.x;
    if (n >= N) return;
    float best = spu[(size_t)n*OUT]; int bi = 0;
    #pragma unroll
    for (int k = 1; k < OUT; k++) {
        float v = spu[(size_t)n*OUT + k];
        if (v > best) { best = v; bi = k; }
    }
    maxv[n] = best; amax[n] = bi;
    if (best >= 0.9f) atomicOr(&flags[1], 1);
}

__global__ void k_finalize(const float* __restrict__ mf, const float* __restrict__ ori,
                           const float* __restrict__ maxv, const int* __restrict__ amax,
                           const int* __restrict__ flags,
                           float* __restrict__ out_trust, float* __restrict__ out_mf,
                           float* __restrict__ out_ori, float* __restrict__ out_pre) {
    int n = blockIdx.x * 256 + threadIdx.x;
    if (n >= N) return;
    float mv = maxv[n];
    bool tr = flags[1] ? (mv >= 0.9f) : (mv >= 0.85f);
    float m = tr ? 1.f : 0.f;
    out_trust[n] = m;
    const float4* src = (const float4*)(mf + (size_t)n * C);
    float4* dst = (float4*)(out_mf + (size_t)n * C);
    #pragma unroll
    for (int c = 0; c < 24; c++) {
        float4 v = src[c];
        v.x *= m; v.y *= m; v.z *= m; v.w *= m;
        dst[c] = v;
    }
    out_ori[n*3]   = ori[n*3]   * m;
    out_ori[n*3+1] = ori[n*3+1] * m;
    out_ori[n*3+2] = ori[n*3+2] * m;
    int bi = amax[n];
    #pragma unroll
    for (int k = 0; k < OUT; k++) out_pre[(size_t)n*OUT + k] = (k == bi) ? m : 0.f;
}

// ---------------------------------------------------------------- launch
extern "C" void kernel_launch(void* const* d_in, const int* in_sizes, int n_in,
                              void* d_out, int out_size, void* d_ws, size_t ws_size,
                              hipStream_t stream) {
    (void)in_sizes; (void)n_in; (void)out_size; (void)ws_size;
    const float* ssf     = (const float*)d_in[0];
    const float* scoords = (const float*)d_in[1];
    const float* gt      = (const float*)d_in[2];
    const float* svp     = (const float*)d_in[3];
    const float* mf      = (const float*)d_in[4];
    const float* ori     = (const float*)d_in[5];
    const float* posses  = (const float*)d_in[6];
    const int*   ran     = (const int*)d_in[7];

    float* out = (float*)d_out;
    float* out_trust = out;
    float* out_mf    = out_trust + N;
    float* out_ori   = out_mf + (size_t)N*C;
    float* out_pre   = out_ori + (size_t)N*3;
    float* out_uw    = out_pre + (size_t)N*OUT;
    float* out_spu   = out_uw  + (size_t)N*OUT;
    float* out_smi   = out_spu + (size_t)N*OUT;

    char* ws = (char*)d_ws;
    float*     w_diff  = (float*)(ws + OFF_DIFF);
    float*     w_al    = (float*)(ws + OFF_AL);
    float*     w_nmf2  = (float*)(ws + OFF_NMF2);
    float*     w_updf  = (float*)(ws + OFF_UPDF);
    int*       w_gtc   = (int*)(ws + OFF_GTC);
    int*       w_smi   = (int*)(ws + OFF_SMI);
    int*       w_perm  = (int*)(ws + OFF_PERM);
    _Float16*  w_aP    = (_Float16*)(ws + OFF_AP);
    _Float16*  w_bQ    = (_Float16*)(ws + OFF_BQ);
    _Float16*  w_mfP   = (_Float16*)(ws + OFF_MFP);
    _Float16*  w_midQ  = (_Float16*)(ws + OFF_MIDQ);
    float*     w_midn2 = (float*)(ws + OFF_MIDN2);
    float*     w_midc  = (float*)(ws + OFF_MIDC);
    int*       w_cls   = (int*)(ws + OFF_CLS);
    float*     w_pav   = (float*)(ws + OFF_PAV);
    int*       w_pai   = (int*)(ws + OFF_PAI);
    float*     w_pb    = (float*)(ws + OFF_PB);
    float*     w_vals  = (float*)(ws + OFF_VALS);
    int*       w_pos   = (int*)(ws + OFF_POS);
    float*     w_maxv  = (float*)(ws + OFF_MAXV);
    int*       w_amax  = (int*)(ws + OFF_AMAX);
    int*       w_flags = (int*)(ws + OFF_FLAGS);
    int*       w_cnt   = (int*)(ws + OFF_CNT);
    int*       w_meta  = (int*)(ws + OFF_META);

    hipMemsetAsync(w_pos, 0xFF, (size_t)N*4, stream);   // -1
    hipMemsetAsync(w_flags, 0, 8, stream);
    hipMemsetAsync(w_cnt, 0, OUT*4, stream);

    k_diff<<<1, 64, 0, stream>>>(posses, w_diff);
    k_prep_m<<<M/32, 64, 0, stream>>>(ssf, scoords, gt, ran, w_diff,
                                      w_al, w_aP, w_updf, w_gtc, w_cnt);
    k_prep_n<<<N/32, 64, 0, stream>>>(mf, w_bQ, w_mfP, w_nmf2);
    k_argmin<<<dim3(M/128, NSPA), 1024, 0, stream>>>(w_aP, w_bQ, w_al, ori, w_pav, w_pai);
    k_argmin_reduce<<<M/256, 256, 0, stream>>>(w_pav, w_pai, w_smi, out_smi);
    k_scan<<<1, 64, 0, stream>>>(w_cnt, w_meta);
    k_permute<<<M/256, 256, 0, stream>>>(w_gtc, w_updf, w_meta, w_perm);
    k_gather_sorted<<<((M+256)*24)/256, 256, 0, stream>>>(w_meta, w_perm, w_smi, w_gtc,
                                                          w_mfP, w_nmf2, ori,
                                                          w_midQ, w_midn2, w_midc, w_cls);
    k_uw<<<dim3(N/128, NSPB), 1024, 0, stream>>>(w_mfP, w_midQ, w_nmf2, ori,
                                                 w_midn2, w_midc, w_cls, w_meta, w_pb);
    k_uw_final<<<N/256, 256, 0, stream>>>(w_pb, svp, out_uw, out_spu);
    k_scatter_pre<<<LG/256, 256, 0, stream>>>(w_smi, w_gtc, out_spu, w_vals, w_pos, w_flags);
    k_scatter_apply<<<LG/256, 256, 0, stream>>>(w_smi, w_gtc, w_vals, w_pos, w_flags, out_spu);
    k_trust_pre<<<N/256, 256, 0, stream>>>(out_spu, w_maxv, w_amax, w_flags);
    k_finalize<<<N/256, 256, 0, stream>>>(mf, ori, w_maxv, w_amax, w_flags,
                                          out_trust, out_mf, out_ori, out_pre);
}

// Round 4
// 265.379 us; speedup vs baseline: 1.8597x; 1.0266x over previous
//
#include <hip/hip_runtime.h>
#include <math.h>

#define N 8192
#define M 8192
#define C 96
#define OUT 20
#define LG 2048

#define KP2 192     // stored K per row: [hi(96)|lo(96)] fp16, 24 h8 slots
#define NSPA 4      // y-slices pass A (256 blocks = 1/CU)
#define NSPB 4      // y-slices pass B (256 blocks = 1/CU)

typedef _Float16 h8 __attribute__((ext_vector_type(8)));
typedef float    f4 __attribute__((ext_vector_type(4)));

// async global->LDS, 16B per lane, no VGPR round-trip (m97 path)
__device__ __forceinline__ void gl_lds16(const h8* g, h8* l) {
    __builtin_amdgcn_global_load_lds(
        (const __attribute__((address_space(1))) unsigned int*)g,
        (__attribute__((address_space(3))) unsigned int*)l,
        16, 0, 0);
}

// tile-slot-major h8 index: rows grouped in 128-row tiles, slot-major inside
__device__ __forceinline__ size_t tsm24(int row, int slot) {
    return ((size_t)(row >> 7) * 24 + slot) * 128 + (row & 127);
}

// ---------------- workspace layout (bytes, all 256-aligned) ----------------
constexpr size_t OFF_DIFF  = 0;
constexpr size_t OFF_AL    = 256;
constexpr size_t OFF_UPDF  = OFF_AL    + (size_t)M*3*4;
constexpr size_t OFF_GTC   = OFF_UPDF  + (size_t)M*4;
constexpr size_t OFF_SMI   = OFF_GTC   + (size_t)M*4;
constexpr size_t OFF_PERM  = OFF_SMI   + (size_t)M*4;
constexpr size_t OFF_AP    = OFF_PERM  + (size_t)M*4;            // M x 192 fp16 (tsm24)
constexpr size_t OFF_BQ    = OFF_AP    + (size_t)M*KP2*2;        // N x 192 fp16
constexpr size_t OFF_MFP   = OFF_BQ    + (size_t)N*KP2*2;        // N x 192 fp16
constexpr size_t OFF_MIDQ  = OFF_MFP   + (size_t)N*KP2*2;        // (M+256) x 192 fp16
constexpr size_t OFF_PAV   = OFF_MIDQ  + (size_t)(M+256)*KP2*2;  // NSPA x M
constexpr size_t OFF_PAI   = OFF_PAV   + (size_t)NSPA*M*4;
constexpr size_t OFF_PB    = OFF_PAI   + (size_t)NSPA*M*4;       // NSPB x N x 20
constexpr size_t OFF_VALS  = OFF_PB    + (size_t)NSPB*N*OUT*4;
constexpr size_t OFF_POS   = OFF_VALS  + (size_t)LG*4;
constexpr size_t OFF_MAXV  = OFF_POS   + (size_t)N*4;
constexpr size_t OFF_AMAX  = OFF_MAXV  + (size_t)N*4;
constexpr size_t OFF_FLAGS = OFF_AMAX  + (size_t)N*4;
constexpr size_t OFF_CNT   = OFF_FLAGS + 256;
constexpr size_t OFF_META  = OFF_CNT   + 256;   // [0]=Mact [1]=nmacro [2..21]=cursor
constexpr size_t OFF_NQ4   = OFF_META  + 256;                    // N x float4 {ox,oy,oz,nmf2}
constexpr size_t OFF_SIDEQ = OFF_NQ4   + (size_t)N*16;           // (M+256) x float4 {m2,mx,my,mz}
constexpr size_t OFF_SIDEC = OFF_SIDEQ + (size_t)(M+256)*16;     // (M+256) int cls

// ---------------------------------------------------------------- 4x4 inverse
__global__ void k_diff(const float* __restrict__ posses, float* __restrict__ diff) {
    if (threadIdx.x != 0 || blockIdx.x != 0) return;
    float a[4][8];
    for (int i = 0; i < 4; i++)
        for (int j = 0; j < 4; j++) {
            a[i][j]     = posses[16 + i*4 + j];
            a[i][4 + j] = (i == j) ? 1.f : 0.f;
        }
    for (int col = 0; col < 4; col++) {
        int piv = col; float mx = fabsf(a[col][col]);
        for (int r = col + 1; r < 4; r++) {
            float v = fabsf(a[r][col]);
            if (v > mx) { mx = v; piv = r; }
        }
        if (piv != col)
            for (int j = 0; j < 8; j++) { float t = a[col][j]; a[col][j] = a[piv][j]; a[piv][j] = t; }
        float inv = 1.0f / a[col][col];
        for (int j = 0; j < 8; j++) a[col][j] *= inv;
        for (int r = 0; r < 4; r++) {
            if (r == col) continue;
            float f = a[r][col];
            for (int j = 0; j < 8; j++) a[r][j] -= f * a[col][j];
        }
    }
    for (int i = 0; i < 4; i++)
        for (int j = 0; j < 4; j++) {
            float s = 0.f;
            for (int k = 0; k < 4; k++) s += a[i][4 + k] * posses[k*4 + j];
            diff[i*4 + j] = s;
        }
}

// ---------------------------------------------------------------- per-m prep (+ class hist)
__global__ void k_prep_m(const float* __restrict__ ssf, const float* __restrict__ scoords,
                         const float* __restrict__ gt, const int* __restrict__ ran_mask,
                         const float* __restrict__ diff,
                         float* __restrict__ al, _Float16* __restrict__ aP,
                         float* __restrict__ updf, int* __restrict__ gtcls,
                         int* __restrict__ cnt) {
    __shared__ int hcnt[OUT];
    const int tt = threadIdx.x;          // 0..63
    if (tt < OUT) hcnt[tt] = 0;
    __syncthreads();
    const int m = blockIdx.x * 32 + (tt >> 1);
    const int h = tt & 1;
    {
        const float4* r4 = (const float4*)(ssf + (size_t)m * C);
        float4 row[12]; float s = 0.f;
        #pragma unroll
        for (int c = 0; c < 12; c++) {
            float4 v = r4[h*12 + c];
            row[c] = v;
            s += v.x*v.x + v.y*v.y + v.z*v.z + v.w*v.w;
        }
        s += __shfl_xor(s, 1, 64);
        float scale = 256.0f / sqrtf(s);
        h8* dst = (h8*)aP;
        #pragma unroll
        for (int qq = 0; qq < 6; qq++) {
            int q = h*6 + qq;
            float4 u = row[2*qq], v = row[2*qq+1];
            float xs[8] = {u.x,u.y,u.z,u.w,v.x,v.y,v.z,v.w};
            h8 hi, lo;
            #pragma unroll
            for (int e = 0; e < 8; e++) {
                float xv = xs[e] * scale;
                _Float16 hh = (_Float16)xv;
                hi[e] = hh;
                lo[e] = (_Float16)(xv - (float)hh);
            }
            dst[tsm24(m, q)]      = hi;
            dst[tsm24(m, 12 + q)] = lo;
        }
        if (h == 0) {
            float x = scoords[m*3], y = scoords[m*3+1], z = scoords[m*3+2];
            #pragma unroll
            for (int j = 0; j < 3; j++)
                al[m*3 + j] = diff[j*4+0]*x + diff[j*4+1]*y + diff[j*4+2]*z + diff[j*4+3];
            int best = 0; float bv = gt[(size_t)m*OUT];
            #pragma unroll
            for (int k = 1; k < OUT; k++) {
                float v = gt[(size_t)m*OUT + k];
                if (v > bv) { bv = v; best = k; }
            }
            gtcls[m] = best;
            bool upd = (best < 9 || m < LG || ran_mask[m] == 1);
            updf[m] = upd ? 1.f : 0.f;
            if (upd) atomicAdd(&hcnt[best], 1);
        }
    }
    __syncthreads();
    if (tt < OUT) atomicAdd(&cnt[tt], hcnt[tt]);
}

// ---------------------------------------------------------------- per-n prep (2 threads/row)
__global__ void k_prep_n(const float* __restrict__ mf, const float* __restrict__ ori,
                         _Float16* __restrict__ bQ, _Float16* __restrict__ mfP,
                         float4* __restrict__ nq4) {
    const int tt = threadIdx.x;          // 0..63
    const int n = blockIdx.x * 32 + (tt >> 1);
    const int h = tt & 1;
    const float4* r4 = (const float4*)(mf + (size_t)n * C);
    float4 row[12]; float s = 0.f;
    #pragma unroll
    for (int c = 0; c < 12; c++) {
        float4 v = r4[h*12 + c];
        row[c] = v;
        s += v.x*v.x + v.y*v.y + v.z*v.z + v.w*v.w;
    }
    s += __shfl_xor(s, 1, 64);
    if (h == 0) {
        float4 o;
        o.x = ori[n*3]; o.y = ori[n*3+1]; o.z = ori[n*3+2]; o.w = s;
        nq4[n] = o;
    }
    float scn = 256.0f / sqrtf(s);
    h8* dB = (h8*)bQ;
    h8* dF = (h8*)mfP;
    #pragma unroll
    for (int qq = 0; qq < 6; qq++) {
        int q = h*6 + qq;
        float4 u = row[2*qq], v = row[2*qq+1];
        float xs[8] = {u.x,u.y,u.z,u.w,v.x,v.y,v.z,v.w};
        h8 hiN, loN, hiF, loF;
        #pragma unroll
        for (int e = 0; e < 8; e++) {
            float xn = xs[e] * scn;
            _Float16 hn = (_Float16)xn;
            hiN[e] = hn; loN[e] = (_Float16)(xn - (float)hn);
            float xf = xs[e] * 256.0f;
            _Float16 hf = (_Float16)xf;
            hiF[e] = hf; loF[e] = (_Float16)(xf - (float)hf);
        }
        dB[tsm24(n, q)]    = hiN;
        dB[tsm24(n, 12+q)] = loN;
        dF[tsm24(n, q)]    = hiF;
        dF[tsm24(n, 12+q)] = loF;
    }
}

// ---------------------------------------------------------------- pass A: MFMA argmin
// 1024 threads = 16 waves (4/SIMD). launch_bounds(1024,1): LDS already limits
// to 1 block/CU; the previous ",4" clamped VGPRs to 64 and spilled to scratch.
// Epilogue uses expanded-distance FMA form with packed nq4 {ox,oy,oz,n2} loads.
__global__ __launch_bounds__(1024, 1) void k_argmin(
        const _Float16* __restrict__ aP, const _Float16* __restrict__ bQ,
        const float* __restrict__ al, const float4* __restrict__ nq4,
        float* __restrict__ pav, int* __restrict__ pai) {
    __shared__ h8 sA[24*128];          // 48 KB resident full-K
    __shared__ h8 sB[2*24*128];        // 96 KB (256 n-cols = 2 row-tiles)
    __shared__ float xv[4*128];
    __shared__ int   xi[4*128];
    const int t = threadIdx.x;
    const int wave = t >> 6, lane = t & 63;
    const int col = lane & 15, quad = lane >> 4;
    const int wm = wave >> 2, wn = wave & 3;     // 4m x 4n
    const int m0 = blockIdx.x * 128;
    const int sp = blockIdx.y;

    {   // stage resident A async (3 x 16B per thread)
        const h8* gA = (const h8*)aP + (size_t)blockIdx.x * 3072;
        #pragma unroll
        for (int q = 0; q < 3; q++) gl_lds16(gA + q*1024 + t, sA + q*1024 + t);
    }
    // per-m expanded terms: exp(-2|a-o|^2) = exp(-2|a|^2 + 4 a.o - 2|o|^2)
    float bm2[8], ax4[8], ay4[8], az4[8];
    #pragma unroll
    for (int e = 0; e < 8; e++) {
        int ml = wm*32 + (e>>2)*16 + quad*4 + (e&3);
        float ax = al[(m0+ml)*3+0], ay = al[(m0+ml)*3+1], az = al[(m0+ml)*3+2];
        bm2[e] = -2.0f*(ax*ax + ay*ay + az*az);
        ax4[e] = 4.0f*ax; ay4[e] = 4.0f*ay; az4[e] = 4.0f*az;
    }
    float best[8]; int bidx[8];
    #pragma unroll
    for (int e = 0; e < 8; e++) { best[e] = 3.4e38f; bidx[e] = 0; }

    const h8* gB = (const h8*)bQ;
    f4 acc[2][4];
    for (int u = 0; u < 32/NSPA; u++) {
        const int tile = sp + u*NSPA;
        __syncthreads();                       // prev compute done reading sB
        {
            const h8* g = gB + (size_t)(2*tile) * 3072;
            #pragma unroll
            for (int q = 0; q < 6; q++) gl_lds16(g + q*1024 + t, sB + q*1024 + t);
        }
        __syncthreads();                       // drains vmcnt -> sA/sB visible
        #pragma unroll
        for (int i = 0; i < 2; i++)
            #pragma unroll
            for (int j = 0; j < 4; j++) acc[i][j] = (f4){0.f,0.f,0.f,0.f};

        #pragma unroll
        for (int ks = 0; ks < 3; ks++) {
            const int hs = ks*4 + quad;        // hi slot; lo slot = 12+hs
            h8 ah[2], alo[2], bh[4], blo[4];
            #pragma unroll
            for (int i = 0; i < 2; i++) {
                int ml = wm*32 + i*16 + col;
                ah[i]  = sA[hs*128 + ml];
                alo[i] = sA[(12+hs)*128 + ml];
            }
            #pragma unroll
            for (int j = 0; j < 4; j++) {
                int r = wn*64 + j*16 + col;
                int tb = (r >> 7) * 3072, rl = r & 127;
                bh[j]  = sB[tb + hs*128 + rl];
                blo[j] = sB[tb + (12+hs)*128 + rl];
            }
            #pragma unroll
            for (int i = 0; i < 2; i++)
                #pragma unroll
                for (int j = 0; j < 4; j++) {
                    acc[i][j] = __builtin_amdgcn_mfma_f32_16x16x32_f16(ah[i],  bh[j],  acc[i][j], 0, 0, 0);
                    acc[i][j] = __builtin_amdgcn_mfma_f32_16x16x32_f16(ah[i],  blo[j], acc[i][j], 0, 0, 0);
                    acc[i][j] = __builtin_amdgcn_mfma_f32_16x16x32_f16(alo[i], bh[j],  acc[i][j], 0, 0, 0);
                }
        }
        // epilogue: running per-lane argmin (expanded form, packed loads)
        const int n0t = tile * 256;
        #pragma unroll
        for (int j = 0; j < 4; j++) {
            int n = n0t + wn*64 + j*16 + col;
            float4 o = nq4[n];
            float bn = -2.0f*(o.x*o.x + o.y*o.y + o.z*o.z);
            #pragma unroll
            for (int e = 0; e < 8; e++) {
                float dot = acc[e>>2][j][e&3];
                float c = bm2[e] + bn;
                c = fmaf(az4[e], o.z, c);
                c = fmaf(ay4[e], o.y, c);
                c = fmaf(ax4[e], o.x, c);
                float sim = fmaf(dot, -(1.0f/65536.0f), 2.0f) - __expf(c);
                if (sim < best[e]) { best[e] = sim; bidx[e] = n; }
            }
        }
    }
    // butterfly over 16 col-lanes, once per block
    #pragma unroll
    for (int e = 0; e < 8; e++) {
        float bv = best[e]; int bi = bidx[e];
        #pragma unroll
        for (int d = 1; d < 16; d <<= 1) {
            float ov = __shfl_xor(bv, d, 64);
            int   oi = __shfl_xor(bi, d, 64);
            if (ov < bv || (ov == bv && oi < bi)) { bv = ov; bi = oi; }
        }
        best[e] = bv; bidx[e] = bi;
    }
    if (col == 0) {
        #pragma unroll
        for (int e = 0; e < 8; e++) {
            int ml = wm*32 + (e>>2)*16 + quad*4 + (e&3);
            xv[wn*128 + ml] = best[e];
            xi[wn*128 + ml] = bidx[e];
        }
    }
    __syncthreads();
    if (t < 128) {   // single writer per (sp, m)
        float bv = xv[t]; int bi = xi[t];
        #pragma unroll
        for (int w = 1; w < 4; w++) {
            float v = xv[w*128 + t]; int i2 = xi[w*128 + t];
            if (v < bv || (v == bv && i2 < bi)) { bv = v; bi = i2; }
        }
        pav[(size_t)sp * M + m0 + t] = bv;
        pai[(size_t)sp * M + m0 + t] = bi;
    }
}

__global__ void k_argmin_reduce(const float* __restrict__ pav, const int* __restrict__ pai,
                                int* __restrict__ smi, float* __restrict__ out_smi) {
    int m = blockIdx.x * 256 + threadIdx.x;
    if (m >= M) return;
    float best = 3.4e38f; int bidx = 0;
    for (int sp = 0; sp < NSPA; sp++) {
        float v = pav[(size_t)sp * M + m];
        int   i = pai[(size_t)sp * M + m];
        if (v < best || (v == best && i < bidx)) { best = v; bidx = i; }
    }
    smi[m] = bidx;
    out_smi[m] = (float)bidx;
}

// ---------------------------------------------------------------- scan + permute (counting sort)
__global__ void k_scan(const int* __restrict__ cnt, int* __restrict__ meta) {
    if (threadIdx.x != 0 || blockIdx.x != 0) return;
    int run = 0;
    for (int k = 0; k < OUT; k++) { meta[2 + k] = run; run += cnt[k]; }
    meta[0] = run;
    meta[1] = (run + 255) / 256;      // macro-tiles of 256
}

__global__ void k_permute(const int* __restrict__ gtcls, const float* __restrict__ updf,
                          int* __restrict__ meta, int* __restrict__ perm) {
    int m = blockIdx.x * 256 + threadIdx.x;
    if (m >= M) return;
    if (updf[m] == 0.f) return;
    int pos = atomicAdd(&meta[2 + gtcls[m]], 1);
    perm[pos] = m;
}

// gather sorted+compacted mid rows: one thread per (row, slot); packs per-row
// side data {m2,mx,my,mz} + cls for k_uw.
__global__ void k_gather_sorted(const int* __restrict__ meta, const int* __restrict__ perm,
                                const int* __restrict__ smi, const int* __restrict__ gtcls,
                                const _Float16* __restrict__ mfP, const float4* __restrict__ nq4,
                                _Float16* __restrict__ midQ,
                                float4* __restrict__ sideQ, int* __restrict__ sideC) {
    int tid = blockIdx.x * 256 + threadIdx.x;
    int rr = tid / 24;
    int q  = tid - rr * 24;
    int mact = meta[0];
    int mpad = meta[1] * 256;
    if (rr >= mpad) return;
    h8* dst = (h8*)midQ;
    if (rr < mact) {
        int m = perm[rr];
        int s = smi[m];
        dst[tsm24(rr, q)] = ((const h8*)mfP)[tsm24(s, q)];
        if (q == 0) {
            float4 o = nq4[s];
            float4 sq;
            sq.x = o.w;                       // |feat|^2
            sq.y = o.x; sq.z = o.y; sq.w = o.z;
            sideQ[rr] = sq;
            sideC[rr] = gtcls[m];
        }
    } else {
        dst[tsm24(rr, q)] = (h8)(_Float16)0.f;
        if (q == 0) {
            sideQ[rr] = (float4){1e9f, 0.f, 0.f, 0.f};   // fd=1e9 -> w = 0 exactly
            sideC[rr] = 0;
        }
    }
}

// ---------------------------------------------------------------- pass B: MFMA class-binned sums
// 1024 threads = 16 waves. launch_bounds(1024,1) (de-spill). Expanded-distance
// FMA epilogue with packed sideQ loads; round-0 proven tile/epilogue structure.
__global__ __launch_bounds__(1024, 1) void k_uw(
        const _Float16* __restrict__ mfP, const _Float16* __restrict__ midQ,
        const float4* __restrict__ nq4,
        const float4* __restrict__ sideQ, const int* __restrict__ sideC,
        const int* __restrict__ meta, float* __restrict__ pb) {
    __shared__ h8 sN[24*128];          // 48 KB resident n-rows
    __shared__ h8 sB[2*24*128];        // 96 KB streamed mid macro-tile
    __shared__ float bins[128*21];
    const int t = threadIdx.x;
    const int wave = t >> 6, lane = t & 63;
    const int col = lane & 15, quad = lane >> 4;
    const int wm = wave >> 2, wn = wave & 3;     // 4m x 4n
    const int n0 = blockIdx.x * 128;
    const int sp = blockIdx.y;
    const int nmac = meta[1];

    {   // stage resident n-rows async
        const h8* gN = (const h8*)mfP + (size_t)blockIdx.x * 3072;
        #pragma unroll
        for (int q = 0; q < 3; q++) gl_lds16(gN + q*1024 + t, sN + q*1024 + t);
    }
    for (int i = t; i < 128*21; i += 1024) bins[i] = 0.f;

    // per-n expanded terms: exp(-8|o-m|^2 - 5.556 fd) with
    // -8|o-m|^2 = bnc + 16 o.m + bm
    float nn2[8], ox[8], oy[8], oz[8], bnc[8];
    #pragma unroll
    for (int e = 0; e < 8; e++) {
        int nl = wm*32 + (e>>2)*16 + quad*4 + (e&3);
        float4 q = nq4[n0 + nl];
        nn2[e] = q.w;
        ox[e] = q.x; oy[e] = q.y; oz[e] = q.z;
        bnc[e] = -8.0f*(q.x*q.x + q.y*q.y + q.z*q.z);
    }

    const h8* gB = (const h8*)midQ;
    f4 acc[2][4];
    for (int mt = sp; mt < nmac; mt += NSPB) {
        const int mb = mt * 256;
        __syncthreads();
        {
            const h8* g = gB + (size_t)(2*mt) * 3072;
            #pragma unroll
            for (int q = 0; q < 6; q++) gl_lds16(g + q*1024 + t, sB + q*1024 + t);
        }
        __syncthreads();
        #pragma unroll
        for (int i = 0; i < 2; i++)
            #pragma unroll
            for (int j = 0; j < 4; j++) acc[i][j] = (f4){0.f,0.f,0.f,0.f};

        #pragma unroll
        for (int ks = 0; ks < 3; ks++) {
            const int hs = ks*4 + quad;
            h8 ah[2], alo[2], bh[4], blo[4];
            #pragma unroll
            for (int i = 0; i < 2; i++) {
                int ml = wm*32 + i*16 + col;
                ah[i]  = sN[hs*128 + ml];
                alo[i] = sN[(12+hs)*128 + ml];
            }
            #pragma unroll
            for (int j = 0; j < 4; j++) {
                int r = wn*64 + j*16 + col;
                int tb = (r >> 7) * 3072, rl = r & 127;
                bh[j]  = sB[tb + hs*128 + rl];
                blo[j] = sB[tb + (12+hs)*128 + rl];
            }
            #pragma unroll
            for (int i = 0; i < 2; i++)
                #pragma unroll
                for (int j = 0; j < 4; j++) {
                    acc[i][j] = __builtin_amdgcn_mfma_f32_16x16x32_f16(ah[i],  bh[j],  acc[i][j], 0, 0, 0);
                    acc[i][j] = __builtin_amdgcn_mfma_f32_16x16x32_f16(ah[i],  blo[j], acc[i][j], 0, 0, 0);
                    acc[i][j] = __builtin_amdgcn_mfma_f32_16x16x32_f16(alo[i], bh[j],  acc[i][j], 0, 0, 0);
                }
        }
        // epilogue: fold into class bins (LDS), expanded-FMA math
        {
            float m2[4], mx16[4], my16[4], mz16[4], bm[4]; int pc[4];
            #pragma unroll
            for (int j = 0; j < 4; j++) {
                int mm = mb + wn*64 + j*16 + col;
                float4 sq = sideQ[mm];
                m2[j] = sq.x;
                mx16[j] = 16.0f*sq.y; my16[j] = 16.0f*sq.z; mz16[j] = 16.0f*sq.w;
                bm[j] = -8.0f*(sq.y*sq.y + sq.z*sq.z + sq.w*sq.w);
                pc[j] = sideC[mm];
            }
            int seg0 = sideC[mb + wn*64];
            int seg1 = sideC[mb + wn*64 + 63];
            if (seg0 == seg1) {   // wave's 64 cols uniform class
                #pragma unroll
                for (int e = 0; e < 8; e++) {
                    float rs = 0.f;
                    #pragma unroll
                    for (int j = 0; j < 4; j++) {
                        float dot = acc[e>>2][j][e&3];
                        float tt = fmaf(dot, -2.0f*(1.0f/65536.0f), nn2[e] + m2[j]);
                        float fd = fmaxf(tt, 0.0f);
                        float c = bnc[e] + bm[j];
                        c = fmaf(oz[e], mz16[j], c);
                        c = fmaf(oy[e], my16[j], c);
                        c = fmaf(ox[e], mx16[j], c);
                        rs += __expf(fmaf(fd, -(0.5f/0.09f), c));
                    }
                    rs += __shfl_xor(rs, 1, 64);
                    rs += __shfl_xor(rs, 2, 64);
                    rs += __shfl_xor(rs, 4, 64);
                    rs += __shfl_xor(rs, 8, 64);
                    if (col == 0) {
                        int nl = wm*32 + (e>>2)*16 + quad*4 + (e&3);
                        atomicAdd(&bins[nl*21 + seg0], rs);
                    }
                }
            } else {              // boundary segment: per-lane run-length into LDS
                #pragma unroll
                for (int e = 0; e < 8; e++) {
                    int nl = wm*32 + (e>>2)*16 + quad*4 + (e&3);
                    float cur = 0.f; int cc = -1;
                    #pragma unroll
                    for (int j = 0; j < 4; j++) {
                        float dot = acc[e>>2][j][e&3];
                        float tt = fmaf(dot, -2.0f*(1.0f/65536.0f), nn2[e] + m2[j]);
                        float fd = fmaxf(tt, 0.0f);
                        float c = bnc[e] + bm[j];
                        c = fmaf(oz[e], mz16[j], c);
                        c = fmaf(oy[e], my16[j], c);
                        c = fmaf(ox[e], mx16[j], c);
                        float w = __expf(fmaf(fd, -(0.5f/0.09f), c));
                        if (pc[j] != cc) {
                            if (cc >= 0) atomicAdd(&bins[nl*21 + cc], cur);
                            cc = pc[j]; cur = 0.f;
                        }
                        cur += w;
                    }
                    if (cc >= 0) atomicAdd(&bins[nl*21 + cc], cur);
                }
            }
        }
    }
    __syncthreads();
    for (int i = t; i < 128*OUT; i += 1024) {
        int loc = i / OUT, k = i - loc*OUT;
        pb[((size_t)sp*N + n0 + loc)*OUT + k] = bins[loc*21 + k];
    }
}

__global__ void k_uw_final(const float* __restrict__ pb, const float* __restrict__ svp,
                           float* __restrict__ out_uw, float* __restrict__ out_spu) {
    int n = blockIdx.x * 256 + threadIdx.x;
    if (n >= N) return;
    float s[OUT];
    #pragma unroll
    for (int k = 0; k < OUT; k++) s[k] = 0.f;
    for (int sp = 0; sp < NSPB; sp++) {
        size_t base = ((size_t)sp * N + n) * OUT;
        #pragma unroll
        for (int k = 0; k < OUT; k++) s[k] += pb[base + k];
    }
    float tot = 0.f;
    #pragma unroll
    for (int k = 0; k < OUT; k++) tot += s[k];
    float rden = 1.0f / (tot + 1e-16f);
    float p[OUT]; float mx = -3.4e38f;
    #pragma unroll
    for (int k = 0; k < OUT; k++) { p[k] = svp[(size_t)n*OUT + k]; mx = fmaxf(mx, p[k]); }
    float es = 0.f;
    #pragma unroll
    for (int k = 0; k < OUT; k++) { p[k] = __expf(p[k] - mx); es += p[k]; }
    float res = 1.0f / es;
    #pragma unroll
    for (int k = 0; k < OUT; k++) {
        float uw = s[k] * rden;
        out_uw[(size_t)n*OUT + k] = uw;
        out_spu[(size_t)n*OUT + k] = 0.5f * (p[k] * res) + 0.5f * uw;
    }
}

// ---------------------------------------------------------------- scatter (lg rows, last-wins)
__global__ void k_scatter_pre(const int* __restrict__ smi, const int* __restrict__ gtcls,
                              const float* __restrict__ spu, float* __restrict__ vals,
                              int* __restrict__ pos, int* __restrict__ flags) {
    int i = blockIdx.x * 256 + threadIdx.x;
    if (i >= LG) return;
    int idx = smi[i];
    float v = spu[(size_t)idx*OUT + gtcls[i]];
    vals[i] = v;
    if (v > 0.1f) atomicOr(&flags[0], 1);
    atomicMax(&pos[idx], i);
}

__global__ void k_scatter_apply(const int* __restrict__ smi, const int* __restrict__ gtcls,
                                const float* __restrict__ vals, const int* __restrict__ pos,
                                const int* __restrict__ flags, float* __restrict__ spu) {
    int i = blockIdx.x * 256 + threadIdx.x;
    if (i >= LG) return;
    int idx = smi[i];
    if (pos[idx] != i) return;
    float v = vals[i];
    bool tmp = flags[0] ? (v > 0.1f) : (v > 0.0f);
    if (!tmp) return;
    int cls = gtcls[i];
    #pragma unroll
    for (int k = 0; k < OUT; k++) spu[(size_t)idx*OUT + k] = (k == cls) ? 1.0f : 0.0f;
}

// ---------------------------------------------------------------- trust / finalize
__global__ void k_trust_pre(const float* __restrict__ spu, float* __restrict__ maxv,
                            int* __restrict__ amax, int* __restrict__ flags) {
    int n = blockIdx.x * 256 + threadIdx.x;
    if (n >= N) return;
    float best = spu[(size_t)n*OUT]; int bi = 0;
    #pragma unroll
    for (int k = 1; k < OUT; k++) {
        float v = spu[(size_t)n*OUT + k];
        if (v > best) { best = v; bi = k; }
    }
    maxv[n] = best; amax[n] = bi;
    if (best >= 0.9f) atomicOr(&flags[1], 1);
}

__global__ void k_finalize(const float* __restrict__ mf, const float* __restrict__ ori,
                           const float* __restrict__ maxv, const int* __restrict__ amax,
                           const int* __restrict__ flags,
                           float* __restrict__ out_trust, float* __restrict__ out_mf,
                           float* __restrict__ out_ori, float* __restrict__ out_pre) {
    int n = blockIdx.x * 256 + threadIdx.x;
    if (n >= N) return;
    float mv = maxv[n];
    bool tr = flags[1] ? (mv >= 0.9f) : (mv >= 0.85f);
    float m = tr ? 1.f : 0.f;
    out_trust[n] = m;
    const float4* src = (const float4*)(mf + (size_t)n * C);
    float4* dst = (float4*)(out_mf + (size_t)n * C);
    #pragma unroll
    for (int c = 0; c < 24; c++) {
        float4 v = src[c];
        v.x *= m; v.y *= m; v.z *= m; v.w *= m;
        dst[c] = v;
    }
    out_ori[n*3]   = ori[n*3]   * m;
    out_ori[n*3+1] = ori[n*3+1] * m;
    out_ori[n*3+2] = ori[n*3+2] * m;
    int bi = amax[n];
    #pragma unroll
    for (int k = 0; k < OUT; k++) out_pre[(size_t)n*OUT + k] = (k == bi) ? m : 0.f;
}

// ---------------------------------------------------------------- launch
extern "C" void kernel_launch(void* const* d_in, const int* in_sizes, int n_in,
                              void* d_out, int out_size, void* d_ws, size_t ws_size,
                              hipStream_t stream) {
    (void)in_sizes; (void)n_in; (void)out_size; (void)ws_size;
    const float* ssf     = (const float*)d_in[0];
    const float* scoords = (const float*)d_in[1];
    const float* gt      = (const float*)d_in[2];
    const float* svp     = (const float*)d_in[3];
    const float* mf      = (const float*)d_in[4];
    const float* ori     = (const float*)d_in[5];
    const float* posses  = (const float*)d_in[6];
    const int*   ran     = (const int*)d_in[7];

    float* out = (float*)d_out;
    float* out_trust = out;
    float* out_mf    = out_trust + N;
    float* out_ori   = out_mf + (size_t)N*C;
    float* out_pre   = out_ori + (size_t)N*3;
    float* out_uw    = out_pre + (size_t)N*OUT;
    float* out_spu   = out_uw  + (size_t)N*OUT;
    float* out_smi   = out_spu + (size_t)N*OUT;

    char* ws = (char*)d_ws;
    float*     w_diff  = (float*)(ws + OFF_DIFF);
    float*     w_al    = (float*)(ws + OFF_AL);
    float*     w_updf  = (float*)(ws + OFF_UPDF);
    int*       w_gtc   = (int*)(ws + OFF_GTC);
    int*       w_smi   = (int*)(ws + OFF_SMI);
    int*       w_perm  = (int*)(ws + OFF_PERM);
    _Float16*  w_aP    = (_Float16*)(ws + OFF_AP);
    _Float16*  w_bQ    = (_Float16*)(ws + OFF_BQ);
    _Float16*  w_mfP   = (_Float16*)(ws + OFF_MFP);
    _Float16*  w_midQ  = (_Float16*)(ws + OFF_MIDQ);
    float*     w_pav   = (float*)(ws + OFF_PAV);
    int*       w_pai   = (int*)(ws + OFF_PAI);
    float*     w_pb    = (float*)(ws + OFF_PB);
    float*     w_vals  = (float*)(ws + OFF_VALS);
    int*       w_pos   = (int*)(ws + OFF_POS);
    float*     w_maxv  = (float*)(ws + OFF_MAXV);
    int*       w_amax  = (int*)(ws + OFF_AMAX);
    int*       w_flags = (int*)(ws + OFF_FLAGS);
    int*       w_cnt   = (int*)(ws + OFF_CNT);
    int*       w_meta  = (int*)(ws + OFF_META);
    float4*    w_nq4   = (float4*)(ws + OFF_NQ4);
    float4*    w_sideQ = (float4*)(ws + OFF_SIDEQ);
    int*       w_sideC = (int*)(ws + OFF_SIDEC);

    hipMemsetAsync(w_pos, 0xFF, (size_t)N*4, stream);   // -1
    hipMemsetAsync(w_flags, 0, 8, stream);
    hipMemsetAsync(w_cnt, 0, OUT*4, stream);

    k_diff<<<1, 64, 0, stream>>>(posses, w_diff);
    k_prep_m<<<M/32, 64, 0, stream>>>(ssf, scoords, gt, ran, w_diff,
                                      w_al, w_aP, w_updf, w_gtc, w_cnt);
    k_prep_n<<<N/32, 64, 0, stream>>>(mf, ori, w_bQ, w_mfP, w_nq4);
    k_argmin<<<dim3(M/128, NSPA), 1024, 0, stream>>>(w_aP, w_bQ, w_al, w_nq4, w_pav, w_pai);
    k_argmin_reduce<<<M/256, 256, 0, stream>>>(w_pav, w_pai, w_smi, out_smi);
    k_scan<<<1, 64, 0, stream>>>(w_cnt, w_meta);
    k_permute<<<M/256, 256, 0, stream>>>(w_gtc, w_updf, w_meta, w_perm);
    k_gather_sorted<<<((M+256)*24)/256, 256, 0, stream>>>(w_meta, w_perm, w_smi, w_gtc,
                                                          w_mfP, w_nq4,
                                                          w_midQ, w_sideQ, w_sideC);
    k_uw<<<dim3(N/128, NSPB), 1024, 0, stream>>>(w_mfP, w_midQ, w_nq4,
                                                 w_sideQ, w_sideC, w_meta, w_pb);
    k_uw_final<<<N/256, 256, 0, stream>>>(w_pb, svp, out_uw, out_spu);
    k_scatter_pre<<<LG/256, 256, 0, stream>>>(w_smi, w_gtc, out_spu, w_vals, w_pos, w_flags);
    k_scatter_apply<<<LG/256, 256, 0, stream>>>(w_smi, w_gtc, w_vals, w_pos, w_flags, out_spu);
    k_trust_pre<<<N/256, 256, 0, stream>>>(out_spu, w_maxv, w_amax, w_flags);
    k_finalize<<<N/256, 256, 0, stream>>>(mf, ori, w_maxv, w_amax, w_flags,
                                          out_trust, out_mf, out_ori, out_pre);
}

// Round 5
// 253.900 us; speedup vs baseline: 1.9438x; 1.0452x over previous
//
#include <hip/hip_runtime.h>
#include <math.h>

#define N 8192
#define M 8192
#define C 96
#define OUT 20
#define LG 2048

#define KP2 192     // stored K per row: [hi(96)|lo(96)] fp16, 24 h8 slots
#define NSPA 4      // y-slices pass A (256 blocks = 1/CU)
#define NSPB 4      // y-slices pass B (256 blocks = 1/CU)

typedef _Float16 h8 __attribute__((ext_vector_type(8)));
typedef float    f4 __attribute__((ext_vector_type(4)));

// async global->LDS, 16B per lane, no VGPR round-trip (m97 path)
__device__ __forceinline__ void gl_lds16(const h8* g, h8* l) {
    __builtin_amdgcn_global_load_lds(
        (const __attribute__((address_space(1))) unsigned int*)g,
        (__attribute__((address_space(3))) unsigned int*)l,
        16, 0, 0);
}

// tile-slot-major h8 index: rows grouped in 128-row tiles, slot-major inside
__device__ __forceinline__ size_t tsm24(int row, int slot) {
    return ((size_t)(row >> 7) * 24 + slot) * 128 + (row & 127);
}

// ---------------- workspace layout (bytes, all 256-aligned) ----------------
constexpr size_t OFF_DIFF  = 0;
constexpr size_t OFF_AL    = 256;
constexpr size_t OFF_UPDF  = OFF_AL    + (size_t)M*3*4;
constexpr size_t OFF_GTC   = OFF_UPDF  + (size_t)M*4;
constexpr size_t OFF_SMI   = OFF_GTC   + (size_t)M*4;
constexpr size_t OFF_PERM  = OFF_SMI   + (size_t)M*4;
constexpr size_t OFF_AP    = OFF_PERM  + (size_t)M*4;            // M x 192 fp16 (tsm24)
constexpr size_t OFF_BQ    = OFF_AP    + (size_t)M*KP2*2;        // N x 192 fp16
constexpr size_t OFF_MFP   = OFF_BQ    + (size_t)N*KP2*2;        // N x 192 fp16
constexpr size_t OFF_MIDQ  = OFF_MFP   + (size_t)N*KP2*2;        // (M+256) x 192 fp16
constexpr size_t OFF_PAV   = OFF_MIDQ  + (size_t)(M+256)*KP2*2;  // NSPA x M
constexpr size_t OFF_PAI   = OFF_PAV   + (size_t)NSPA*M*4;
constexpr size_t OFF_PB    = OFF_PAI   + (size_t)NSPA*M*4;       // NSPB x N x 20
constexpr size_t OFF_VALS  = OFF_PB    + (size_t)NSPB*N*OUT*4;
constexpr size_t OFF_POS   = OFF_VALS  + (size_t)LG*4;
constexpr size_t OFF_MAXV  = OFF_POS   + (size_t)N*4;
constexpr size_t OFF_AMAX  = OFF_MAXV  + (size_t)N*4;
constexpr size_t OFF_FLAGS = OFF_AMAX  + (size_t)N*4;
constexpr size_t OFF_CNT   = OFF_FLAGS + 256;
constexpr size_t OFF_META  = OFF_CNT   + 256;   // [0]=Mact [1]=nmacro [2..21]=cursor
constexpr size_t OFF_NQ4   = OFF_META  + 256;                    // N x float4 {ox,oy,oz,nmf2}
constexpr size_t OFF_SIDEQ = OFF_NQ4   + (size_t)N*16;           // (M+256) x float4 {m2,mx,my,mz}
constexpr size_t OFF_SIDEC = OFF_SIDEQ + (size_t)(M+256)*16;     // (M+256) int cls

// ---------------------------------------------------------------- 4x4 inverse
__global__ void k_diff(const float* __restrict__ posses, float* __restrict__ diff) {
    if (threadIdx.x != 0 || blockIdx.x != 0) return;
    float a[4][8];
    for (int i = 0; i < 4; i++)
        for (int j = 0; j < 4; j++) {
            a[i][j]     = posses[16 + i*4 + j];
            a[i][4 + j] = (i == j) ? 1.f : 0.f;
        }
    for (int col = 0; col < 4; col++) {
        int piv = col; float mx = fabsf(a[col][col]);
        for (int r = col + 1; r < 4; r++) {
            float v = fabsf(a[r][col]);
            if (v > mx) { mx = v; piv = r; }
        }
        if (piv != col)
            for (int j = 0; j < 8; j++) { float t = a[col][j]; a[col][j] = a[piv][j]; a[piv][j] = t; }
        float inv = 1.0f / a[col][col];
        for (int j = 0; j < 8; j++) a[col][j] *= inv;
        for (int r = 0; r < 4; r++) {
            if (r == col) continue;
            float f = a[r][col];
            for (int j = 0; j < 8; j++) a[r][j] -= f * a[col][j];
        }
    }
    for (int i = 0; i < 4; i++)
        for (int j = 0; j < 4; j++) {
            float s = 0.f;
            for (int k = 0; k < 4; k++) s += a[i][4 + k] * posses[k*4 + j];
            diff[i*4 + j] = s;
        }
}

// ---------------------------------------------------------------- per-m prep (+ class hist)
__global__ void k_prep_m(const float* __restrict__ ssf, const float* __restrict__ scoords,
                         const float* __restrict__ gt, const int* __restrict__ ran_mask,
                         const float* __restrict__ diff,
                         float* __restrict__ al, _Float16* __restrict__ aP,
                         float* __restrict__ updf, int* __restrict__ gtcls,
                         int* __restrict__ cnt) {
    __shared__ int hcnt[OUT];
    const int tt = threadIdx.x;          // 0..63
    if (tt < OUT) hcnt[tt] = 0;
    __syncthreads();
    const int m = blockIdx.x * 32 + (tt >> 1);
    const int h = tt & 1;
    {
        const float4* r4 = (const float4*)(ssf + (size_t)m * C);
        float4 row[12]; float s = 0.f;
        #pragma unroll
        for (int c = 0; c < 12; c++) {
            float4 v = r4[h*12 + c];
            row[c] = v;
            s += v.x*v.x + v.y*v.y + v.z*v.z + v.w*v.w;
        }
        s += __shfl_xor(s, 1, 64);
        float scale = 256.0f / sqrtf(s);
        h8* dst = (h8*)aP;
        #pragma unroll
        for (int qq = 0; qq < 6; qq++) {
            int q = h*6 + qq;
            float4 u = row[2*qq], v = row[2*qq+1];
            float xs[8] = {u.x,u.y,u.z,u.w,v.x,v.y,v.z,v.w};
            h8 hi, lo;
            #pragma unroll
            for (int e = 0; e < 8; e++) {
                float xv = xs[e] * scale;
                _Float16 hh = (_Float16)xv;
                hi[e] = hh;
                lo[e] = (_Float16)(xv - (float)hh);
            }
            dst[tsm24(m, q)]      = hi;
            dst[tsm24(m, 12 + q)] = lo;
        }
        if (h == 0) {
            float x = scoords[m*3], y = scoords[m*3+1], z = scoords[m*3+2];
            #pragma unroll
            for (int j = 0; j < 3; j++)
                al[m*3 + j] = diff[j*4+0]*x + diff[j*4+1]*y + diff[j*4+2]*z + diff[j*4+3];
            int best = 0; float bv = gt[(size_t)m*OUT];
            #pragma unroll
            for (int k = 1; k < OUT; k++) {
                float v = gt[(size_t)m*OUT + k];
                if (v > bv) { bv = v; best = k; }
            }
            gtcls[m] = best;
            bool upd = (best < 9 || m < LG || ran_mask[m] == 1);
            updf[m] = upd ? 1.f : 0.f;
            if (upd) atomicAdd(&hcnt[best], 1);
        }
    }
    __syncthreads();
    if (tt < OUT) atomicAdd(&cnt[tt], hcnt[tt]);
}

// ---------------------------------------------------------------- per-n prep (2 threads/row)
__global__ void k_prep_n(const float* __restrict__ mf, const float* __restrict__ ori,
                         _Float16* __restrict__ bQ, _Float16* __restrict__ mfP,
                         float4* __restrict__ nq4) {
    const int tt = threadIdx.x;          // 0..63
    const int n = blockIdx.x * 32 + (tt >> 1);
    const int h = tt & 1;
    const float4* r4 = (const float4*)(mf + (size_t)n * C);
    float4 row[12]; float s = 0.f;
    #pragma unroll
    for (int c = 0; c < 12; c++) {
        float4 v = r4[h*12 + c];
        row[c] = v;
        s += v.x*v.x + v.y*v.y + v.z*v.z + v.w*v.w;
    }
    s += __shfl_xor(s, 1, 64);
    if (h == 0) {
        float4 o;
        o.x = ori[n*3]; o.y = ori[n*3+1]; o.z = ori[n*3+2]; o.w = s;
        nq4[n] = o;
    }
    float scn = 256.0f / sqrtf(s);
    h8* dB = (h8*)bQ;
    h8* dF = (h8*)mfP;
    #pragma unroll
    for (int qq = 0; qq < 6; qq++) {
        int q = h*6 + qq;
        float4 u = row[2*qq], v = row[2*qq+1];
        float xs[8] = {u.x,u.y,u.z,u.w,v.x,v.y,v.z,v.w};
        h8 hiN, loN, hiF, loF;
        #pragma unroll
        for (int e = 0; e < 8; e++) {
            float xn = xs[e] * scn;
            _Float16 hn = (_Float16)xn;
            hiN[e] = hn; loN[e] = (_Float16)(xn - (float)hn);
            float xf = xs[e] * 256.0f;
            _Float16 hf = (_Float16)xf;
            hiF[e] = hf; loF[e] = (_Float16)(xf - (float)hf);
        }
        dB[tsm24(n, q)]    = hiN;
        dB[tsm24(n, 12+q)] = loN;
        dF[tsm24(n, q)]    = hiF;
        dF[tsm24(n, 12+q)] = loF;
    }
}

// ---------------------------------------------------------------- pass A: MFMA argmin
// 1024 threads = 16 waves (4/SIMD). VGPR cap at 4 waves/SIMD is 128 TOTAL
// (arch+acc): per-m side terms live in LDS (sMs), read per-e in the epilogue,
// keeping peak register demand ~110 -> spill-free.
__global__ __launch_bounds__(1024, 1) void k_argmin(
        const _Float16* __restrict__ aP, const _Float16* __restrict__ bQ,
        const float* __restrict__ al, const float4* __restrict__ nq4,
        float* __restrict__ pav, int* __restrict__ pai) {
    __shared__ h8 sA[24*128];          // 48 KB resident full-K
    __shared__ h8 sB[2*24*128];        // 96 KB (256 n-cols = 2 row-tiles)
    __shared__ float xv[4*128];
    __shared__ int   xi[4*128];
    __shared__ float4 sMs[128];        // {4ax,4ay,4az,-2|a|^2} per m-row (2 KB)
    const int t = threadIdx.x;
    const int wave = t >> 6, lane = t & 63;
    const int col = lane & 15, quad = lane >> 4;
    const int wm = wave >> 2, wn = wave & 3;     // 4m x 4n
    const int m0 = blockIdx.x * 128;
    const int sp = blockIdx.y;

    {   // stage resident A async (3 x 16B per thread)
        const h8* gA = (const h8*)aP + (size_t)blockIdx.x * 3072;
        #pragma unroll
        for (int q = 0; q < 3; q++) gl_lds16(gA + q*1024 + t, sA + q*1024 + t);
    }
    if (t < 128) {   // per-m expanded terms into LDS (frees 32 VGPRs/thread)
        float ax = al[(m0+t)*3+0], ay = al[(m0+t)*3+1], az = al[(m0+t)*3+2];
        sMs[t] = (float4){4.0f*ax, 4.0f*ay, 4.0f*az, -2.0f*(ax*ax+ay*ay+az*az)};
    }
    float best[8]; int bidx[8];
    #pragma unroll
    for (int e = 0; e < 8; e++) { best[e] = 3.4e38f; bidx[e] = 0; }

    const h8* gB = (const h8*)bQ;
    f4 acc[2][4];
    for (int u = 0; u < 32/NSPA; u++) {
        const int tile = sp + u*NSPA;
        __syncthreads();                       // prev compute done reading sB
        {
            const h8* g = gB + (size_t)(2*tile) * 3072;
            #pragma unroll
            for (int q = 0; q < 6; q++) gl_lds16(g + q*1024 + t, sB + q*1024 + t);
        }
        __syncthreads();                       // drains vmcnt -> sA/sB/sMs visible
        #pragma unroll
        for (int i = 0; i < 2; i++)
            #pragma unroll
            for (int j = 0; j < 4; j++) acc[i][j] = (f4){0.f,0.f,0.f,0.f};

        #pragma unroll
        for (int ks = 0; ks < 3; ks++) {
            const int hs = ks*4 + quad;        // hi slot; lo slot = 12+hs
            h8 ah[2], alo[2], bh[4], blo[4];
            #pragma unroll
            for (int i = 0; i < 2; i++) {
                int ml = wm*32 + i*16 + col;
                ah[i]  = sA[hs*128 + ml];
                alo[i] = sA[(12+hs)*128 + ml];
            }
            #pragma unroll
            for (int j = 0; j < 4; j++) {
                int r = wn*64 + j*16 + col;
                int tb = (r >> 7) * 3072, rl = r & 127;
                bh[j]  = sB[tb + hs*128 + rl];
                blo[j] = sB[tb + (12+hs)*128 + rl];
            }
            #pragma unroll
            for (int i = 0; i < 2; i++)
                #pragma unroll
                for (int j = 0; j < 4; j++) {
                    acc[i][j] = __builtin_amdgcn_mfma_f32_16x16x32_f16(ah[i],  bh[j],  acc[i][j], 0, 0, 0);
                    acc[i][j] = __builtin_amdgcn_mfma_f32_16x16x32_f16(ah[i],  blo[j], acc[i][j], 0, 0, 0);
                    acc[i][j] = __builtin_amdgcn_mfma_f32_16x16x32_f16(alo[i], bh[j],  acc[i][j], 0, 0, 0);
                }
        }
        // epilogue: e-outer, per-m side from LDS (1 float4 live at a time)
        const int n0t = tile * 256;
        float4 o4[4]; float bn[4]; int nidx[4];
        #pragma unroll
        for (int j = 0; j < 4; j++) {
            nidx[j] = n0t + wn*64 + j*16 + col;
            o4[j] = nq4[nidx[j]];
            bn[j] = -2.0f*(o4[j].x*o4[j].x + o4[j].y*o4[j].y + o4[j].z*o4[j].z);
        }
        #pragma unroll
        for (int e = 0; e < 8; e++) {
            int ml = wm*32 + (e>>2)*16 + quad*4 + (e&3);
            float4 sm = sMs[ml];
            #pragma unroll
            for (int j = 0; j < 4; j++) {
                float dot = acc[e>>2][j][e&3];
                float c = sm.w + bn[j];
                c = fmaf(sm.z, o4[j].z, c);
                c = fmaf(sm.y, o4[j].y, c);
                c = fmaf(sm.x, o4[j].x, c);
                float sim = fmaf(dot, -(1.0f/65536.0f), 2.0f) - __expf(c);
                if (sim < best[e]) { best[e] = sim; bidx[e] = nidx[j]; }
            }
        }
    }
    // butterfly over 16 col-lanes, once per block
    #pragma unroll
    for (int e = 0; e < 8; e++) {
        float bv = best[e]; int bi = bidx[e];
        #pragma unroll
        for (int d = 1; d < 16; d <<= 1) {
            float ov = __shfl_xor(bv, d, 64);
            int   oi = __shfl_xor(bi, d, 64);
            if (ov < bv || (ov == bv && oi < bi)) { bv = ov; bi = oi; }
        }
        best[e] = bv; bidx[e] = bi;
    }
    if (col == 0) {
        #pragma unroll
        for (int e = 0; e < 8; e++) {
            int ml = wm*32 + (e>>2)*16 + quad*4 + (e&3);
            xv[wn*128 + ml] = best[e];
            xi[wn*128 + ml] = bidx[e];
        }
    }
    __syncthreads();
    if (t < 128) {   // single writer per (sp, m)
        float bv = xv[t]; int bi = xi[t];
        #pragma unroll
        for (int w = 1; w < 4; w++) {
            float v = xv[w*128 + t]; int i2 = xi[w*128 + t];
            if (v < bv || (v == bv && i2 < bi)) { bv = v; bi = i2; }
        }
        pav[(size_t)sp * M + m0 + t] = bv;
        pai[(size_t)sp * M + m0 + t] = bi;
    }
}

__global__ void k_argmin_reduce(const float* __restrict__ pav, const int* __restrict__ pai,
                                int* __restrict__ smi, float* __restrict__ out_smi) {
    int m = blockIdx.x * 256 + threadIdx.x;
    if (m >= M) return;
    float best = 3.4e38f; int bidx = 0;
    for (int sp = 0; sp < NSPA; sp++) {
        float v = pav[(size_t)sp * M + m];
        int   i = pai[(size_t)sp * M + m];
        if (v < best || (v == best && i < bidx)) { best = v; bidx = i; }
    }
    smi[m] = bidx;
    out_smi[m] = (float)bidx;
}

// ---------------------------------------------------------------- scan + permute (counting sort)
__global__ void k_scan(const int* __restrict__ cnt, int* __restrict__ meta) {
    if (threadIdx.x != 0 || blockIdx.x != 0) return;
    int run = 0;
    for (int k = 0; k < OUT; k++) { meta[2 + k] = run; run += cnt[k]; }
    meta[0] = run;
    meta[1] = (run + 255) / 256;      // macro-tiles of 256
}

__global__ void k_permute(const int* __restrict__ gtcls, const float* __restrict__ updf,
                          int* __restrict__ meta, int* __restrict__ perm) {
    int m = blockIdx.x * 256 + threadIdx.x;
    if (m >= M) return;
    if (updf[m] == 0.f) return;
    int pos = atomicAdd(&meta[2 + gtcls[m]], 1);
    perm[pos] = m;
}

// gather sorted+compacted mid rows: one thread per (row, slot); packs per-row
// side data {m2,mx,my,mz} + cls for k_uw.
__global__ void k_gather_sorted(const int* __restrict__ meta, const int* __restrict__ perm,
                                const int* __restrict__ smi, const int* __restrict__ gtcls,
                                const _Float16* __restrict__ mfP, const float4* __restrict__ nq4,
                                _Float16* __restrict__ midQ,
                                float4* __restrict__ sideQ, int* __restrict__ sideC) {
    int tid = blockIdx.x * 256 + threadIdx.x;
    int rr = tid / 24;
    int q  = tid - rr * 24;
    int mact = meta[0];
    int mpad = meta[1] * 256;
    if (rr >= mpad) return;
    h8* dst = (h8*)midQ;
    if (rr < mact) {
        int m = perm[rr];
        int s = smi[m];
        dst[tsm24(rr, q)] = ((const h8*)mfP)[tsm24(s, q)];
        if (q == 0) {
            float4 o = nq4[s];
            float4 sq;
            sq.x = o.w;                       // |feat|^2
            sq.y = o.x; sq.z = o.y; sq.w = o.z;
            sideQ[rr] = sq;
            sideC[rr] = gtcls[m];
        }
    } else {
        dst[tsm24(rr, q)] = (h8)(_Float16)0.f;
        if (q == 0) {
            sideQ[rr] = (float4){1e9f, 0.f, 0.f, 0.f};   // fd=1e9 -> w = 0 exactly
            sideC[rr] = 0;
        }
    }
}

// ---------------------------------------------------------------- pass B: MFMA class-binned sums
// 1024 threads = 16 waves. Per-n side terms live in LDS (sSa/sSb), read per-e
// in the epilogue -> peak register demand ~115 (under the 128 cap), spill-free.
__global__ __launch_bounds__(1024, 1) void k_uw(
        const _Float16* __restrict__ mfP, const _Float16* __restrict__ midQ,
        const float4* __restrict__ nq4,
        const float4* __restrict__ sideQ, const int* __restrict__ sideC,
        const int* __restrict__ meta, float* __restrict__ pb) {
    __shared__ h8 sN[24*128];          // 48 KB resident n-rows
    __shared__ h8 sB[2*24*128];        // 96 KB streamed mid macro-tile
    __shared__ float bins[128*21];
    __shared__ float4 sSa[128];        // {ox,oy,oz,-8|o|^2} per n-row (2 KB)
    __shared__ float  sSb[128];        // nmf2 per n-row (0.5 KB)
    const int t = threadIdx.x;
    const int wave = t >> 6, lane = t & 63;
    const int col = lane & 15, quad = lane >> 4;
    const int wm = wave >> 2, wn = wave & 3;     // 4m x 4n
    const int n0 = blockIdx.x * 128;
    const int sp = blockIdx.y;
    const int nmac = meta[1];

    {   // stage resident n-rows async
        const h8* gN = (const h8*)mfP + (size_t)blockIdx.x * 3072;
        #pragma unroll
        for (int q = 0; q < 3; q++) gl_lds16(gN + q*1024 + t, sN + q*1024 + t);
    }
    if (t < 128) {   // per-n expanded terms into LDS (frees 40 VGPRs/thread)
        float4 q = nq4[n0 + t];
        sSa[t] = (float4){q.x, q.y, q.z, -8.0f*(q.x*q.x + q.y*q.y + q.z*q.z)};
        sSb[t] = q.w;
    }
    for (int i = t; i < 128*21; i += 1024) bins[i] = 0.f;

    const h8* gB = (const h8*)midQ;
    f4 acc[2][4];
    for (int mt = sp; mt < nmac; mt += NSPB) {
        const int mb = mt * 256;
        __syncthreads();
        {
            const h8* g = gB + (size_t)(2*mt) * 3072;
            #pragma unroll
            for (int q = 0; q < 6; q++) gl_lds16(g + q*1024 + t, sB + q*1024 + t);
        }
        __syncthreads();
        #pragma unroll
        for (int i = 0; i < 2; i++)
            #pragma unroll
            for (int j = 0; j < 4; j++) acc[i][j] = (f4){0.f,0.f,0.f,0.f};

        #pragma unroll
        for (int ks = 0; ks < 3; ks++) {
            const int hs = ks*4 + quad;
            h8 ah[2], alo[2], bh[4], blo[4];
            #pragma unroll
            for (int i = 0; i < 2; i++) {
                int ml = wm*32 + i*16 + col;
                ah[i]  = sN[hs*128 + ml];
                alo[i] = sN[(12+hs)*128 + ml];
            }
            #pragma unroll
            for (int j = 0; j < 4; j++) {
                int r = wn*64 + j*16 + col;
                int tb = (r >> 7) * 3072, rl = r & 127;
                bh[j]  = sB[tb + hs*128 + rl];
                blo[j] = sB[tb + (12+hs)*128 + rl];
            }
            #pragma unroll
            for (int i = 0; i < 2; i++)
                #pragma unroll
                for (int j = 0; j < 4; j++) {
                    acc[i][j] = __builtin_amdgcn_mfma_f32_16x16x32_f16(ah[i],  bh[j],  acc[i][j], 0, 0, 0);
                    acc[i][j] = __builtin_amdgcn_mfma_f32_16x16x32_f16(ah[i],  blo[j], acc[i][j], 0, 0, 0);
                    acc[i][j] = __builtin_amdgcn_mfma_f32_16x16x32_f16(alo[i], bh[j],  acc[i][j], 0, 0, 0);
                }
        }
        // epilogue: fold into class bins; e-outer, per-n side from LDS
        {
            float m2[4], mx16[4], my16[4], mz16[4], bm[4]; int pc[4];
            #pragma unroll
            for (int j = 0; j < 4; j++) {
                int mm = mb + wn*64 + j*16 + col;
                float4 sq = sideQ[mm];
                m2[j] = sq.x;
                mx16[j] = 16.0f*sq.y; my16[j] = 16.0f*sq.z; mz16[j] = 16.0f*sq.w;
                bm[j] = -8.0f*(sq.y*sq.y + sq.z*sq.z + sq.w*sq.w);
                pc[j] = sideC[mm];
            }
            int seg0 = sideC[mb + wn*64];
            int seg1 = sideC[mb + wn*64 + 63];
            if (seg0 == seg1) {   // wave's 64 cols uniform class
                #pragma unroll
                for (int e = 0; e < 8; e++) {
                    int nl = wm*32 + (e>>2)*16 + quad*4 + (e&3);
                    float4 sa = sSa[nl];
                    float nn = sSb[nl];
                    float rs = 0.f;
                    #pragma unroll
                    for (int j = 0; j < 4; j++) {
                        float dot = acc[e>>2][j][e&3];
                        float tt = fmaf(dot, -2.0f*(1.0f/65536.0f), nn + m2[j]);
                        float fd = fmaxf(tt, 0.0f);
                        float c = sa.w + bm[j];
                        c = fmaf(sa.z, mz16[j], c);
                        c = fmaf(sa.y, my16[j], c);
                        c = fmaf(sa.x, mx16[j], c);
                        rs += __expf(fmaf(fd, -(0.5f/0.09f), c));
                    }
                    rs += __shfl_xor(rs, 1, 64);
                    rs += __shfl_xor(rs, 2, 64);
                    rs += __shfl_xor(rs, 4, 64);
                    rs += __shfl_xor(rs, 8, 64);
                    if (col == 0) atomicAdd(&bins[nl*21 + seg0], rs);
                }
            } else {              // boundary segment: per-lane run-length into LDS
                #pragma unroll
                for (int e = 0; e < 8; e++) {
                    int nl = wm*32 + (e>>2)*16 + quad*4 + (e&3);
                    float4 sa = sSa[nl];
                    float nn = sSb[nl];
                    float cur = 0.f; int cc = -1;
                    #pragma unroll
                    for (int j = 0; j < 4; j++) {
                        float dot = acc[e>>2][j][e&3];
                        float tt = fmaf(dot, -2.0f*(1.0f/65536.0f), nn + m2[j]);
                        float fd = fmaxf(tt, 0.0f);
                        float c = sa.w + bm[j];
                        c = fmaf(sa.z, mz16[j], c);
                        c = fmaf(sa.y, my16[j], c);
                        c = fmaf(sa.x, mx16[j], c);
                        float w = __expf(fmaf(fd, -(0.5f/0.09f), c));
                        if (pc[j] != cc) {
                            if (cc >= 0) atomicAdd(&bins[nl*21 + cc], cur);
                            cc = pc[j]; cur = 0.f;
                        }
                        cur += w;
                    }
                    if (cc >= 0) atomicAdd(&bins[nl*21 + cc], cur);
                }
            }
        }
    }
    __syncthreads();
    for (int i = t; i < 128*OUT; i += 1024) {
        int loc = i / OUT, k = i - loc*OUT;
        pb[((size_t)sp*N + n0 + loc)*OUT + k] = bins[loc*21 + k];
    }
}

__global__ void k_uw_final(const float* __restrict__ pb, const float* __restrict__ svp,
                           float* __restrict__ out_uw, float* __restrict__ out_spu) {
    int n = blockIdx.x * 256 + threadIdx.x;
    if (n >= N) return;
    float s[OUT];
    #pragma unroll
    for (int k = 0; k < OUT; k++) s[k] = 0.f;
    for (int sp = 0; sp < NSPB; sp++) {
        size_t base = ((size_t)sp * N + n) * OUT;
        #pragma unroll
        for (int k = 0; k < OUT; k++) s[k] += pb[base + k];
    }
    float tot = 0.f;
    #pragma unroll
    for (int k = 0; k < OUT; k++) tot += s[k];
    float rden = 1.0f / (tot + 1e-16f);
    float p[OUT]; float mx = -3.4e38f;
    #pragma unroll
    for (int k = 0; k < OUT; k++) { p[k] = svp[(size_t)n*OUT + k]; mx = fmaxf(mx, p[k]); }
    float es = 0.f;
    #pragma unroll
    for (int k = 0; k < OUT; k++) { p[k] = __expf(p[k] - mx); es += p[k]; }
    float res = 1.0f / es;
    #pragma unroll
    for (int k = 0; k < OUT; k++) {
        float uw = s[k] * rden;
        out_uw[(size_t)n*OUT + k] = uw;
        out_spu[(size_t)n*OUT + k] = 0.5f * (p[k] * res) + 0.5f * uw;
    }
}

// ---------------------------------------------------------------- scatter (lg rows, last-wins)
__global__ void k_scatter_pre(const int* __restrict__ smi, const int* __restrict__ gtcls,
                              const float* __restrict__ spu, float* __restrict__ vals,
                              int* __restrict__ pos, int* __restrict__ flags) {
    int i = blockIdx.x * 256 + threadIdx.x;
    if (i >= LG) return;
    int idx = smi[i];
    float v = spu[(size_t)idx*OUT + gtcls[i]];
    vals[i] = v;
    if (v > 0.1f) atomicOr(&flags[0], 1);
    atomicMax(&pos[idx], i);
}

__global__ void k_scatter_apply(const int* __restrict__ smi, const int* __restrict__ gtcls,
                                const float* __restrict__ vals, const int* __restrict__ pos,
                                const int* __restrict__ flags, float* __restrict__ spu) {
    int i = blockIdx.x * 256 + threadIdx.x;
    if (i >= LG) return;
    int idx = smi[i];
    if (pos[idx] != i) return;
    float v = vals[i];
    bool tmp = flags[0] ? (v > 0.1f) : (v > 0.0f);
    if (!tmp) return;
    int cls = gtcls[i];
    #pragma unroll
    for (int k = 0; k < OUT; k++) spu[(size_t)idx*OUT + k] = (k == cls) ? 1.0f : 0.0f;
}

// ---------------------------------------------------------------- trust / finalize
__global__ void k_trust_pre(const float* __restrict__ spu, float* __restrict__ maxv,
                            int* __restrict__ amax, int* __restrict__ flags) {
    int n = blockIdx.x * 256 + threadIdx.x;
    if (n >= N) return;
    float best = spu[(size_t)n*OUT]; int bi = 0;
    #pragma unroll
    for (int k = 1; k < OUT; k++) {
        float v = spu[(size_t)n*OUT + k];
        if (v > best) { best = v; bi = k; }
    }
    maxv[n] = best; amax[n] = bi;
    if (best >= 0.9f) atomicOr(&flags[1], 1);
}

__global__ void k_finalize(const float* __restrict__ mf, const float* __restrict__ ori,
                           const float* __restrict__ maxv, const int* __restrict__ amax,
                           const int* __restrict__ flags,
                           float* __restrict__ out_trust, float* __restrict__ out_mf,
                           float* __restrict__ out_ori, float* __restrict__ out_pre) {
    int n = blockIdx.x * 256 + threadIdx.x;
    if (n >= N) return;
    float mv = maxv[n];
    bool tr = flags[1] ? (mv >= 0.9f) : (mv >= 0.85f);
    float m = tr ? 1.f : 0.f;
    out_trust[n] = m;
    const float4* src = (const float4*)(mf + (size_t)n * C);
    float4* dst = (float4*)(out_mf + (size_t)n * C);
    #pragma unroll
    for (int c = 0; c < 24; c++) {
        float4 v = src[c];
        v.x *= m; v.y *= m; v.z *= m; v.w *= m;
        dst[c] = v;
    }
    out_ori[n*3]   = ori[n*3]   * m;
    out_ori[n*3+1] = ori[n*3+1] * m;
    out_ori[n*3+2] = ori[n*3+2] * m;
    int bi = amax[n];
    #pragma unroll
    for (int k = 0; k < OUT; k++) out_pre[(size_t)n*OUT + k] = (k == bi) ? m : 0.f;
}

// ---------------------------------------------------------------- launch
extern "C" void kernel_launch(void* const* d_in, const int* in_sizes, int n_in,
                              void* d_out, int out_size, void* d_ws, size_t ws_size,
                              hipStream_t stream) {
    (void)in_sizes; (void)n_in; (void)out_size; (void)ws_size;
    const float* ssf     = (const float*)d_in[0];
    const float* scoords = (const float*)d_in[1];
    const float* gt      = (const float*)d_in[2];
    const float* svp     = (const float*)d_in[3];
    const float* mf      = (const float*)d_in[4];
    const float* ori     = (const float*)d_in[5];
    const float* posses  = (const float*)d_in[6];
    const int*   ran     = (const int*)d_in[7];

    float* out = (float*)d_out;
    float* out_trust = out;
    float* out_mf    = out_trust + N;
    float* out_ori   = out_mf + (size_t)N*C;
    float* out_pre   = out_ori + (size_t)N*3;
    float* out_uw    = out_pre + (size_t)N*OUT;
    float* out_spu   = out_uw  + (size_t)N*OUT;
    float* out_smi   = out_spu + (size_t)N*OUT;

    char* ws = (char*)d_ws;
    float*     w_diff  = (float*)(ws + OFF_DIFF);
    float*     w_al    = (float*)(ws + OFF_AL);
    float*     w_updf  = (float*)(ws + OFF_UPDF);
    int*       w_gtc   = (int*)(ws + OFF_GTC);
    int*       w_smi   = (int*)(ws + OFF_SMI);
    int*       w_perm  = (int*)(ws + OFF_PERM);
    _Float16*  w_aP    = (_Float16*)(ws + OFF_AP);
    _Float16*  w_bQ    = (_Float16*)(ws + OFF_BQ);
    _Float16*  w_mfP   = (_Float16*)(ws + OFF_MFP);
    _Float16*  w_midQ  = (_Float16*)(ws + OFF_MIDQ);
    float*     w_pav   = (float*)(ws + OFF_PAV);
    int*       w_pai   = (int*)(ws + OFF_PAI);
    float*     w_pb    = (float*)(ws + OFF_PB);
    float*     w_vals  = (float*)(ws + OFF_VALS);
    int*       w_pos   = (int*)(ws + OFF_POS);
    float*     w_maxv  = (float*)(ws + OFF_MAXV);
    int*       w_amax  = (int*)(ws + OFF_AMAX);
    int*       w_flags = (int*)(ws + OFF_FLAGS);
    int*       w_cnt   = (int*)(ws + OFF_CNT);
    int*       w_meta  = (int*)(ws + OFF_META);
    float4*    w_nq4   = (float4*)(ws + OFF_NQ4);
    float4*    w_sideQ = (float4*)(ws + OFF_SIDEQ);
    int*       w_sideC = (int*)(ws + OFF_SIDEC);

    hipMemsetAsync(w_pos, 0xFF, (size_t)N*4, stream);   // -1
    hipMemsetAsync(w_flags, 0, 8, stream);
    hipMemsetAsync(w_cnt, 0, OUT*4, stream);

    k_diff<<<1, 64, 0, stream>>>(posses, w_diff);
    k_prep_m<<<M/32, 64, 0, stream>>>(ssf, scoords, gt, ran, w_diff,
                                      w_al, w_aP, w_updf, w_gtc, w_cnt);
    k_prep_n<<<N/32, 64, 0, stream>>>(mf, ori, w_bQ, w_mfP, w_nq4);
    k_argmin<<<dim3(M/128, NSPA), 1024, 0, stream>>>(w_aP, w_bQ, w_al, w_nq4, w_pav, w_pai);
    k_argmin_reduce<<<M/256, 256, 0, stream>>>(w_pav, w_pai, w_smi, out_smi);
    k_scan<<<1, 64, 0, stream>>>(w_cnt, w_meta);
    k_permute<<<M/256, 256, 0, stream>>>(w_gtc, w_updf, w_meta, w_perm);
    k_gather_sorted<<<((M+256)*24)/256, 256, 0, stream>>>(w_meta, w_perm, w_smi, w_gtc,
                                                          w_mfP, w_nq4,
                                                          w_midQ, w_sideQ, w_sideC);
    k_uw<<<dim3(N/128, NSPB), 1024, 0, stream>>>(w_mfP, w_midQ, w_nq4,
                                                 w_sideQ, w_sideC, w_meta, w_pb);
    k_uw_final<<<N/256, 256, 0, stream>>>(w_pb, svp, out_uw, out_spu);
    k_scatter_pre<<<LG/256, 256, 0, stream>>>(w_smi, w_gtc, out_spu, w_vals, w_pos, w_flags);
    k_scatter_apply<<<LG/256, 256, 0, stream>>>(w_smi, w_gtc, w_vals, w_pos, w_flags, out_spu);
    k_trust_pre<<<N/256, 256, 0, stream>>>(out_spu, w_maxv, w_amax, w_flags);
    k_finalize<<<N/256, 256, 0, stream>>>(mf, ori, w_maxv, w_amax, w_flags,
                                          out_trust, out_mf, out_ori, out_pre);
}

// Round 6
// 228.311 us; speedup vs baseline: 2.1616x; 1.1121x over previous
//
#include <hip/hip_runtime.h>
#include <math.h>

#define N 8192
#define M 8192
#define C 96
#define OUT 20
#define LG 2048

#define KP2 192     // stored K per row: [hi(96)|lo(96)] fp16, 24 h8 slots
#define NSPA 4      // y-slices pass A (256 blocks = 1/CU)
#define NSPB 4      // y-slices pass B (256 blocks = 1/CU)

typedef _Float16 h8 __attribute__((ext_vector_type(8)));
typedef float    f4 __attribute__((ext_vector_type(4)));

// async global->LDS, 16B per lane, no VGPR round-trip (m97 path)
__device__ __forceinline__ void gl_lds16(const h8* g, h8* l) {
    __builtin_amdgcn_global_load_lds(
        (const __attribute__((address_space(1))) unsigned int*)g,
        (__attribute__((address_space(3))) unsigned int*)l,
        16, 0, 0);
}

// tile-slot-major h8 index: rows grouped in 128-row tiles, slot-major inside
__device__ __forceinline__ size_t tsm24(int row, int slot) {
    return ((size_t)(row >> 7) * 24 + slot) * 128 + (row & 127);
}

// ---------------- workspace layout (bytes, all 256-aligned) ----------------
constexpr size_t OFF_DIFF  = 0;
constexpr size_t OFF_AL    = 256;
constexpr size_t OFF_UPDF  = OFF_AL    + (size_t)M*3*4;
constexpr size_t OFF_GTC   = OFF_UPDF  + (size_t)M*4;
constexpr size_t OFF_SMI   = OFF_GTC   + (size_t)M*4;
constexpr size_t OFF_PERM  = OFF_SMI   + (size_t)M*4;
constexpr size_t OFF_AP    = OFF_PERM  + (size_t)M*4;            // M x 192 fp16 (tsm24)
constexpr size_t OFF_BQ    = OFF_AP    + (size_t)M*KP2*2;        // N x 192 fp16
constexpr size_t OFF_MFP   = OFF_BQ    + (size_t)N*KP2*2;        // N x 192 fp16
constexpr size_t OFF_MIDH  = OFF_MFP   + (size_t)N*KP2*2;        // (M+256) x 12 hi slots
constexpr size_t OFF_PAV   = OFF_MIDH  + (size_t)(M+256)*192;    // NSPA x M
constexpr size_t OFF_PAI   = OFF_PAV   + (size_t)NSPA*M*4;
constexpr size_t OFF_PB    = OFF_PAI   + (size_t)NSPA*M*4;       // NSPB x N x 20
constexpr size_t OFF_VALS  = OFF_PB    + (size_t)NSPB*N*OUT*4;
constexpr size_t OFF_POS   = OFF_VALS  + (size_t)LG*4;
constexpr size_t OFF_MAXV  = OFF_POS   + (size_t)N*4;
constexpr size_t OFF_AMAX  = OFF_MAXV  + (size_t)N*4;
constexpr size_t OFF_FLAGS = OFF_AMAX  + (size_t)N*4;
constexpr size_t OFF_CNT   = OFF_FLAGS + 256;
constexpr size_t OFF_META  = OFF_CNT   + 256;   // [0]=Mact [1]=nmacro [2..21]=cursor
constexpr size_t OFF_NQ4   = OFF_META  + 256;                    // N x float4 {ox,oy,oz,nmf2}
constexpr size_t OFF_SIDEQ = OFF_NQ4   + (size_t)N*16;           // (M+256) x float4 {m2,mx,my,mz}
constexpr size_t OFF_SIDEC = OFF_SIDEQ + (size_t)(M+256)*16;     // (M+256) int cls

// ---------------------------------------------------------------- 4x4 inverse
__global__ void k_diff(const float* __restrict__ posses, float* __restrict__ diff) {
    if (threadIdx.x != 0 || blockIdx.x != 0) return;
    float a[4][8];
    for (int i = 0; i < 4; i++)
        for (int j = 0; j < 4; j++) {
            a[i][j]     = posses[16 + i*4 + j];
            a[i][4 + j] = (i == j) ? 1.f : 0.f;
        }
    for (int col = 0; col < 4; col++) {
        int piv = col; float mx = fabsf(a[col][col]);
        for (int r = col + 1; r < 4; r++) {
            float v = fabsf(a[r][col]);
            if (v > mx) { mx = v; piv = r; }
        }
        if (piv != col)
            for (int j = 0; j < 8; j++) { float t = a[col][j]; a[col][j] = a[piv][j]; a[piv][j] = t; }
        float inv = 1.0f / a[col][col];
        for (int j = 0; j < 8; j++) a[col][j] *= inv;
        for (int r = 0; r < 4; r++) {
            if (r == col) continue;
            float f = a[r][col];
            for (int j = 0; j < 8; j++) a[r][j] -= f * a[col][j];
        }
    }
    for (int i = 0; i < 4; i++)
        for (int j = 0; j < 4; j++) {
            float s = 0.f;
            for (int k = 0; k < 4; k++) s += a[i][4 + k] * posses[k*4 + j];
            diff[i*4 + j] = s;
        }
}

// ---------------------------------------------------------------- per-m prep (+ class hist)
__global__ void k_prep_m(const float* __restrict__ ssf, const float* __restrict__ scoords,
                         const float* __restrict__ gt, const int* __restrict__ ran_mask,
                         const float* __restrict__ diff,
                         float* __restrict__ al, _Float16* __restrict__ aP,
                         float* __restrict__ updf, int* __restrict__ gtcls,
                         int* __restrict__ cnt) {
    __shared__ int hcnt[OUT];
    const int tt = threadIdx.x;          // 0..63
    if (tt < OUT) hcnt[tt] = 0;
    __syncthreads();
    const int m = blockIdx.x * 32 + (tt >> 1);
    const int h = tt & 1;
    {
        const float4* r4 = (const float4*)(ssf + (size_t)m * C);
        float4 row[12]; float s = 0.f;
        #pragma unroll
        for (int c = 0; c < 12; c++) {
            float4 v = r4[h*12 + c];
            row[c] = v;
            s += v.x*v.x + v.y*v.y + v.z*v.z + v.w*v.w;
        }
        s += __shfl_xor(s, 1, 64);
        float scale = 256.0f / sqrtf(s);
        h8* dst = (h8*)aP;
        #pragma unroll
        for (int qq = 0; qq < 6; qq++) {
            int q = h*6 + qq;
            float4 u = row[2*qq], v = row[2*qq+1];
            float xs[8] = {u.x,u.y,u.z,u.w,v.x,v.y,v.z,v.w};
            h8 hi, lo;
            #pragma unroll
            for (int e = 0; e < 8; e++) {
                float xv = xs[e] * scale;
                _Float16 hh = (_Float16)xv;
                hi[e] = hh;
                lo[e] = (_Float16)(xv - (float)hh);
            }
            dst[tsm24(m, q)]      = hi;
            dst[tsm24(m, 12 + q)] = lo;
        }
        if (h == 0) {
            float x = scoords[m*3], y = scoords[m*3+1], z = scoords[m*3+2];
            #pragma unroll
            for (int j = 0; j < 3; j++)
                al[m*3 + j] = diff[j*4+0]*x + diff[j*4+1]*y + diff[j*4+2]*z + diff[j*4+3];
            int best = 0; float bv = gt[(size_t)m*OUT];
            #pragma unroll
            for (int k = 1; k < OUT; k++) {
                float v = gt[(size_t)m*OUT + k];
                if (v > bv) { bv = v; best = k; }
            }
            gtcls[m] = best;
            bool upd = (best < 9 || m < LG || ran_mask[m] == 1);
            updf[m] = upd ? 1.f : 0.f;
            if (upd) atomicAdd(&hcnt[best], 1);
        }
    }
    __syncthreads();
    if (tt < OUT) atomicAdd(&cnt[tt], hcnt[tt]);
}

// ---------------------------------------------------------------- per-n prep (2 threads/row)
__global__ void k_prep_n(const float* __restrict__ mf, const float* __restrict__ ori,
                         _Float16* __restrict__ bQ, _Float16* __restrict__ mfP,
                         float4* __restrict__ nq4) {
    const int tt = threadIdx.x;          // 0..63
    const int n = blockIdx.x * 32 + (tt >> 1);
    const int h = tt & 1;
    const float4* r4 = (const float4*)(mf + (size_t)n * C);
    float4 row[12]; float s = 0.f;
    #pragma unroll
    for (int c = 0; c < 12; c++) {
        float4 v = r4[h*12 + c];
        row[c] = v;
        s += v.x*v.x + v.y*v.y + v.z*v.z + v.w*v.w;
    }
    s += __shfl_xor(s, 1, 64);
    if (h == 0) {
        float4 o;
        o.x = ori[n*3]; o.y = ori[n*3+1]; o.z = ori[n*3+2]; o.w = s;
        nq4[n] = o;
    }
    float scn = 256.0f / sqrtf(s);
    h8* dB = (h8*)bQ;
    h8* dF = (h8*)mfP;
    #pragma unroll
    for (int qq = 0; qq < 6; qq++) {
        int q = h*6 + qq;
        float4 u = row[2*qq], v = row[2*qq+1];
        float xs[8] = {u.x,u.y,u.z,u.w,v.x,v.y,v.z,v.w};
        h8 hiN, loN, hiF, loF;
        #pragma unroll
        for (int e = 0; e < 8; e++) {
            float xn = xs[e] * scn;
            _Float16 hn = (_Float16)xn;
            hiN[e] = hn; loN[e] = (_Float16)(xn - (float)hn);
            float xf = xs[e] * 256.0f;
            _Float16 hf = (_Float16)xf;
            hiF[e] = hf; loF[e] = (_Float16)(xf - (float)hf);
        }
        dB[tsm24(n, q)]    = hiN;
        dB[tsm24(n, 12+q)] = loN;
        dF[tsm24(n, q)]    = hiF;
        dF[tsm24(n, 12+q)] = loF;
    }
}

// ---------------------------------------------------------------- pass A: MFMA argmin
// UNCHANGED from round 5 (clean attribution for the k_uw changes).
__global__ __launch_bounds__(1024, 1) void k_argmin(
        const _Float16* __restrict__ aP, const _Float16* __restrict__ bQ,
        const float* __restrict__ al, const float4* __restrict__ nq4,
        float* __restrict__ pav, int* __restrict__ pai) {
    __shared__ h8 sA[24*128];          // 48 KB resident full-K
    __shared__ h8 sB[2*24*128];        // 96 KB (256 n-cols = 2 row-tiles)
    __shared__ float xv[4*128];
    __shared__ int   xi[4*128];
    __shared__ float4 sMs[128];        // {4ax,4ay,4az,-2|a|^2} per m-row (2 KB)
    const int t = threadIdx.x;
    const int wave = t >> 6, lane = t & 63;
    const int col = lane & 15, quad = lane >> 4;
    const int wm = wave >> 2, wn = wave & 3;     // 4m x 4n
    const int m0 = blockIdx.x * 128;
    const int sp = blockIdx.y;

    {   // stage resident A async (3 x 16B per thread)
        const h8* gA = (const h8*)aP + (size_t)blockIdx.x * 3072;
        #pragma unroll
        for (int q = 0; q < 3; q++) gl_lds16(gA + q*1024 + t, sA + q*1024 + t);
    }
    if (t < 128) {   // per-m expanded terms into LDS
        float ax = al[(m0+t)*3+0], ay = al[(m0+t)*3+1], az = al[(m0+t)*3+2];
        sMs[t] = (float4){4.0f*ax, 4.0f*ay, 4.0f*az, -2.0f*(ax*ax+ay*ay+az*az)};
    }
    float best[8]; int bidx[8];
    #pragma unroll
    for (int e = 0; e < 8; e++) { best[e] = 3.4e38f; bidx[e] = 0; }

    const h8* gB = (const h8*)bQ;
    f4 acc[2][4];
    for (int u = 0; u < 32/NSPA; u++) {
        const int tile = sp + u*NSPA;
        __syncthreads();                       // prev compute done reading sB
        {
            const h8* g = gB + (size_t)(2*tile) * 3072;
            #pragma unroll
            for (int q = 0; q < 6; q++) gl_lds16(g + q*1024 + t, sB + q*1024 + t);
        }
        __syncthreads();                       // drains vmcnt -> sA/sB/sMs visible
        #pragma unroll
        for (int i = 0; i < 2; i++)
            #pragma unroll
            for (int j = 0; j < 4; j++) acc[i][j] = (f4){0.f,0.f,0.f,0.f};

        #pragma unroll
        for (int ks = 0; ks < 3; ks++) {
            const int hs = ks*4 + quad;        // hi slot; lo slot = 12+hs
            h8 ah[2], alo[2], bh[4], blo[4];
            #pragma unroll
            for (int i = 0; i < 2; i++) {
                int ml = wm*32 + i*16 + col;
                ah[i]  = sA[hs*128 + ml];
                alo[i] = sA[(12+hs)*128 + ml];
            }
            #pragma unroll
            for (int j = 0; j < 4; j++) {
                int r = wn*64 + j*16 + col;
                int tb = (r >> 7) * 3072, rl = r & 127;
                bh[j]  = sB[tb + hs*128 + rl];
                blo[j] = sB[tb + (12+hs)*128 + rl];
            }
            #pragma unroll
            for (int i = 0; i < 2; i++)
                #pragma unroll
                for (int j = 0; j < 4; j++) {
                    acc[i][j] = __builtin_amdgcn_mfma_f32_16x16x32_f16(ah[i],  bh[j],  acc[i][j], 0, 0, 0);
                    acc[i][j] = __builtin_amdgcn_mfma_f32_16x16x32_f16(ah[i],  blo[j], acc[i][j], 0, 0, 0);
                    acc[i][j] = __builtin_amdgcn_mfma_f32_16x16x32_f16(alo[i], bh[j],  acc[i][j], 0, 0, 0);
                }
        }
        // epilogue: e-outer, per-m side from LDS (1 float4 live at a time)
        const int n0t = tile * 256;
        float4 o4[4]; float bn[4]; int nidx[4];
        #pragma unroll
        for (int j = 0; j < 4; j++) {
            nidx[j] = n0t + wn*64 + j*16 + col;
            o4[j] = nq4[nidx[j]];
            bn[j] = -2.0f*(o4[j].x*o4[j].x + o4[j].y*o4[j].y + o4[j].z*o4[j].z);
        }
        #pragma unroll
        for (int e = 0; e < 8; e++) {
            int ml = wm*32 + (e>>2)*16 + quad*4 + (e&3);
            float4 sm = sMs[ml];
            #pragma unroll
            for (int j = 0; j < 4; j++) {
                float dot = acc[e>>2][j][e&3];
                float c = sm.w + bn[j];
                c = fmaf(sm.z, o4[j].z, c);
                c = fmaf(sm.y, o4[j].y, c);
                c = fmaf(sm.x, o4[j].x, c);
                float sim = fmaf(dot, -(1.0f/65536.0f), 2.0f) - __expf(c);
                if (sim < best[e]) { best[e] = sim; bidx[e] = nidx[j]; }
            }
        }
    }
    // butterfly over 16 col-lanes, once per block
    #pragma unroll
    for (int e = 0; e < 8; e++) {
        float bv = best[e]; int bi = bidx[e];
        #pragma unroll
        for (int d = 1; d < 16; d <<= 1) {
            float ov = __shfl_xor(bv, d, 64);
            int   oi = __shfl_xor(bi, d, 64);
            if (ov < bv || (ov == bv && oi < bi)) { bv = ov; bi = oi; }
        }
        best[e] = bv; bidx[e] = bi;
    }
    if (col == 0) {
        #pragma unroll
        for (int e = 0; e < 8; e++) {
            int ml = wm*32 + (e>>2)*16 + quad*4 + (e&3);
            xv[wn*128 + ml] = best[e];
            xi[wn*128 + ml] = bidx[e];
        }
    }
    __syncthreads();
    if (t < 128) {   // single writer per (sp, m)
        float bv = xv[t]; int bi = xi[t];
        #pragma unroll
        for (int w = 1; w < 4; w++) {
            float v = xv[w*128 + t]; int i2 = xi[w*128 + t];
            if (v < bv || (v == bv && i2 < bi)) { bv = v; bi = i2; }
        }
        pav[(size_t)sp * M + m0 + t] = bv;
        pai[(size_t)sp * M + m0 + t] = bi;
    }
}

__global__ void k_argmin_reduce(const float* __restrict__ pav, const int* __restrict__ pai,
                                int* __restrict__ smi, float* __restrict__ out_smi) {
    int m = blockIdx.x * 256 + threadIdx.x;
    if (m >= M) return;
    float best = 3.4e38f; int bidx = 0;
    for (int sp = 0; sp < NSPA; sp++) {
        float v = pav[(size_t)sp * M + m];
        int   i = pai[(size_t)sp * M + m];
        if (v < best || (v == best && i < bidx)) { best = v; bidx = i; }
    }
    smi[m] = bidx;
    out_smi[m] = (float)bidx;
}

// ---------------------------------------------------------------- scan + permute (counting sort)
__global__ void k_scan(const int* __restrict__ cnt, int* __restrict__ meta) {
    if (threadIdx.x != 0 || blockIdx.x != 0) return;
    int run = 0;
    for (int k = 0; k < OUT; k++) { meta[2 + k] = run; run += cnt[k]; }
    meta[0] = run;
    meta[1] = (run + 255) / 256;      // macro-tiles of 256
}

__global__ void k_permute(const int* __restrict__ gtcls, const float* __restrict__ updf,
                          int* __restrict__ meta, int* __restrict__ perm) {
    int m = blockIdx.x * 256 + threadIdx.x;
    if (m >= M) return;
    if (updf[m] == 0.f) return;
    int pos = atomicAdd(&meta[2 + gtcls[m]], 1);
    perm[pos] = m;
}

// gather sorted+compacted mid rows, HI SLOTS ONLY (12/row) into compact midH
// (tsm12 layout); packs per-row side data {m2,mx,my,mz} + cls for k_uw.
__global__ void k_gather_sorted(const int* __restrict__ meta, const int* __restrict__ perm,
                                const int* __restrict__ smi, const int* __restrict__ gtcls,
                                const _Float16* __restrict__ mfP, const float4* __restrict__ nq4,
                                _Float16* __restrict__ midH,
                                float4* __restrict__ sideQ, int* __restrict__ sideC) {
    int tid = blockIdx.x * 256 + threadIdx.x;
    int rr = tid / 12;
    int q  = tid - rr * 12;          // hi slot 0..11
    int mact = meta[0];
    int mpad = meta[1] * 256;
    if (rr >= mpad) return;
    h8* dst = (h8*)midH;
    size_t didx = ((size_t)(rr >> 7) * 12 + q) * 128 + (rr & 127);
    if (rr < mact) {
        int m = perm[rr];
        int s = smi[m];
        dst[didx] = ((const h8*)mfP)[tsm24(s, q)];
        if (q == 0) {
            float4 o = nq4[s];
            float4 sq;
            sq.x = o.w;                       // |feat|^2
            sq.y = o.x; sq.z = o.y; sq.w = o.z;
            sideQ[rr] = sq;
            sideC[rr] = gtcls[m];
        }
    } else {
        dst[didx] = (h8)(_Float16)0.f;
        if (q == 0) {
            sideQ[rr] = (float4){1e9f, 0.f, 0.f, 0.f};   // fd=1e9 -> w = 0 exactly
            sideC[rr] = 0;
        }
    }
}

// ---------------------------------------------------------------- pass B: MFMA class-binned sums
// Changes vs round 5: (1) boundary epilogue = contiguous class-range masked
// shfl-reduce, ONE atomic per (quad,class) — kills the 16-way same-address
// LDS atomic chains; (2) B side hi-only (2 MFMA: (ah+alo)*bh), streamed from
// compact midH (48 KB/tile); (3) double-buffered sB, one barrier per tile.
__global__ __launch_bounds__(1024, 1) void k_uw(
        const _Float16* __restrict__ mfP, const _Float16* __restrict__ midH,
        const float4* __restrict__ nq4,
        const float4* __restrict__ sideQ, const int* __restrict__ sideC,
        const int* __restrict__ meta, float* __restrict__ pb) {
    __shared__ h8 sN[24*128];          // 48 KB resident n-rows (hi+lo)
    __shared__ h8 sB[2][2*12*128];     // 2 x 48 KB streamed mid tiles (hi only, 256 cols)
    __shared__ float bins[128*21];
    __shared__ float4 sSa[128];        // {ox,oy,oz,-8|o|^2} per n-row (2 KB)
    __shared__ float  sSb[128];        // nmf2 per n-row (0.5 KB)
    const int t = threadIdx.x;
    const int wave = t >> 6, lane = t & 63;
    const int col = lane & 15, quad = lane >> 4;
    const int wm = wave >> 2, wn = wave & 3;     // 4m x 4n
    const int n0 = blockIdx.x * 128;
    const int sp = blockIdx.y;
    const int nmac = meta[1];

    {   // stage resident n-rows + first streamed tile async
        const h8* gN = (const h8*)mfP + (size_t)blockIdx.x * 3072;
        #pragma unroll
        for (int q = 0; q < 3; q++) gl_lds16(gN + q*1024 + t, sN + q*1024 + t);
        if (sp < nmac) {
            const h8* g = (const h8*)midH + (size_t)(2*sp) * 1536;
            #pragma unroll
            for (int q = 0; q < 3; q++) gl_lds16(g + q*1024 + t, sB[0] + q*1024 + t);
        }
    }
    if (t < 128) {   // per-n expanded terms into LDS
        float4 q = nq4[n0 + t];
        sSa[t] = (float4){q.x, q.y, q.z, -8.0f*(q.x*q.x + q.y*q.y + q.z*q.z)};
        sSb[t] = q.w;
    }
    for (int i = t; i < 128*21; i += 1024) bins[i] = 0.f;

    __syncthreads();                   // drains vmcnt: sN + sB[0] + side + bins

    int cur = 0;
    f4 acc[2][4];
    for (int mt = sp; mt < nmac; mt += NSPB) {
        const int mb = mt * 256;
        if (mt + NSPB < nmac) {        // prefetch next tile into other buffer
            const h8* g = (const h8*)midH + (size_t)(2*(mt + NSPB)) * 1536;
            #pragma unroll
            for (int q = 0; q < 3; q++) gl_lds16(g + q*1024 + t, sB[cur^1] + q*1024 + t);
        }
        #pragma unroll
        for (int i = 0; i < 2; i++)
            #pragma unroll
            for (int j = 0; j < 4; j++) acc[i][j] = (f4){0.f,0.f,0.f,0.f};

        const h8* sBc = sB[cur];
        #pragma unroll
        for (int ks = 0; ks < 3; ks++) {
            const int hs = ks*4 + quad;        // hi slot 0..11
            h8 ah[2], alo[2], bh[4];
            #pragma unroll
            for (int i = 0; i < 2; i++) {
                int ml = wm*32 + i*16 + col;
                ah[i]  = sN[hs*128 + ml];
                alo[i] = sN[(12+hs)*128 + ml];
            }
            #pragma unroll
            for (int j = 0; j < 4; j++) {
                int r = wn*64 + j*16 + col;
                int tb = (r >> 7) * 1536, rl = r & 127;
                bh[j]  = sBc[tb + hs*128 + rl];
            }
            #pragma unroll
            for (int i = 0; i < 2; i++)
                #pragma unroll
                for (int j = 0; j < 4; j++) {
                    acc[i][j] = __builtin_amdgcn_mfma_f32_16x16x32_f16(ah[i],  bh[j], acc[i][j], 0, 0, 0);
                    acc[i][j] = __builtin_amdgcn_mfma_f32_16x16x32_f16(alo[i], bh[j], acc[i][j], 0, 0, 0);
                }
        }
        // epilogue: fold into class bins
        {
            float m2[4], mx16[4], my16[4], mz16[4], bm[4]; int pc[4];
            #pragma unroll
            for (int j = 0; j < 4; j++) {
                int mm = mb + wn*64 + j*16 + col;
                float4 sq = sideQ[mm];
                m2[j] = sq.x;
                mx16[j] = 16.0f*sq.y; my16[j] = 16.0f*sq.z; mz16[j] = 16.0f*sq.w;
                bm[j] = -8.0f*(sq.y*sq.y + sq.z*sq.z + sq.w*sq.w);
                pc[j] = sideC[mm];
            }
            int seg0 = sideC[mb + wn*64];
            int seg1 = sideC[mb + wn*64 + 63];
            if (seg0 == seg1) {   // wave's 64 cols uniform class
                #pragma unroll
                for (int e = 0; e < 8; e++) {
                    int nl = wm*32 + (e>>2)*16 + quad*4 + (e&3);
                    float4 sa = sSa[nl];
                    float nn = sSb[nl];
                    float rs = 0.f;
                    #pragma unroll
                    for (int j = 0; j < 4; j++) {
                        float dot = acc[e>>2][j][e&3];
                        float tt = fmaf(dot, -2.0f*(1.0f/65536.0f), nn + m2[j]);
                        float fd = fmaxf(tt, 0.0f);
                        float c = sa.w + bm[j];
                        c = fmaf(sa.z, mz16[j], c);
                        c = fmaf(sa.y, my16[j], c);
                        c = fmaf(sa.x, mx16[j], c);
                        rs += __expf(fmaf(fd, -(0.5f/0.09f), c));
                    }
                    rs += __shfl_xor(rs, 1, 64);
                    rs += __shfl_xor(rs, 2, 64);
                    rs += __shfl_xor(rs, 4, 64);
                    rs += __shfl_xor(rs, 8, 64);
                    if (col == 0) atomicAdd(&bins[nl*21 + seg0], rs);
                }
            } else {
                // boundary: classes in window form the contiguous range
                // [seg0,seg1] (counting sort) -> masked shfl-reduce per class,
                // ONE atomic per (quad,class). No per-lane atomic chains.
                #pragma unroll
                for (int e = 0; e < 8; e++) {
                    int nl = wm*32 + (e>>2)*16 + quad*4 + (e&3);
                    float4 sa = sSa[nl];
                    float nn = sSb[nl];
                    float w[4];
                    #pragma unroll
                    for (int j = 0; j < 4; j++) {
                        float dot = acc[e>>2][j][e&3];
                        float tt = fmaf(dot, -2.0f*(1.0f/65536.0f), nn + m2[j]);
                        float fd = fmaxf(tt, 0.0f);
                        float c = sa.w + bm[j];
                        c = fmaf(sa.z, mz16[j], c);
                        c = fmaf(sa.y, my16[j], c);
                        c = fmaf(sa.x, mx16[j], c);
                        w[j] = __expf(fmaf(fd, -(0.5f/0.09f), c));
                    }
                    for (int cc = seg0; cc <= seg1; cc++) {
                        float rs = 0.f;
                        #pragma unroll
                        for (int j = 0; j < 4; j++) rs += (pc[j] == cc) ? w[j] : 0.f;
                        rs += __shfl_xor(rs, 1, 64);
                        rs += __shfl_xor(rs, 2, 64);
                        rs += __shfl_xor(rs, 4, 64);
                        rs += __shfl_xor(rs, 8, 64);
                        if (col == 0) atomicAdd(&bins[nl*21 + cc], rs);
                    }
                }
            }
        }
        __syncthreads();   // prefetch landed + all waves done reading sB[cur]
        cur ^= 1;
    }
    __syncthreads();
    for (int i = t; i < 128*OUT; i += 1024) {
        int loc = i / OUT, k = i - loc*OUT;
        pb[((size_t)sp*N + n0 + loc)*OUT + k] = bins[loc*21 + k];
    }
}

__global__ void k_uw_final(const float* __restrict__ pb, const float* __restrict__ svp,
                           float* __restrict__ out_uw, float* __restrict__ out_spu) {
    int n = blockIdx.x * 256 + threadIdx.x;
    if (n >= N) return;
    float s[OUT];
    #pragma unroll
    for (int k = 0; k < OUT; k++) s[k] = 0.f;
    for (int sp = 0; sp < NSPB; sp++) {
        size_t base = ((size_t)sp * N + n) * OUT;
        #pragma unroll
        for (int k = 0; k < OUT; k++) s[k] += pb[base + k];
    }
    float tot = 0.f;
    #pragma unroll
    for (int k = 0; k < OUT; k++) tot += s[k];
    float rden = 1.0f / (tot + 1e-16f);
    float p[OUT]; float mx = -3.4e38f;
    #pragma unroll
    for (int k = 0; k < OUT; k++) { p[k] = svp[(size_t)n*OUT + k]; mx = fmaxf(mx, p[k]); }
    float es = 0.f;
    #pragma unroll
    for (int k = 0; k < OUT; k++) { p[k] = __expf(p[k] - mx); es += p[k]; }
    float res = 1.0f / es;
    #pragma unroll
    for (int k = 0; k < OUT; k++) {
        float uw = s[k] * rden;
        out_uw[(size_t)n*OUT + k] = uw;
        out_spu[(size_t)n*OUT + k] = 0.5f * (p[k] * res) + 0.5f * uw;
    }
}

// ---------------------------------------------------------------- scatter (lg rows, last-wins)
__global__ void k_scatter_pre(const int* __restrict__ smi, const int* __restrict__ gtcls,
                              const float* __restrict__ spu, float* __restrict__ vals,
                              int* __restrict__ pos, int* __restrict__ flags) {
    int i = blockIdx.x * 256 + threadIdx.x;
    if (i >= LG) return;
    int idx = smi[i];
    float v = spu[(size_t)idx*OUT + gtcls[i]];
    vals[i] = v;
    if (v > 0.1f) atomicOr(&flags[0], 1);
    atomicMax(&pos[idx], i);
}

__global__ void k_scatter_apply(const int* __restrict__ smi, const int* __restrict__ gtcls,
                                const float* __restrict__ vals, const int* __restrict__ pos,
                                const int* __restrict__ flags, float* __restrict__ spu) {
    int i = blockIdx.x * 256 + threadIdx.x;
    if (i >= LG) return;
    int idx = smi[i];
    if (pos[idx] != i) return;
    float v = vals[i];
    bool tmp = flags[0] ? (v > 0.1f) : (v > 0.0f);
    if (!tmp) return;
    int cls = gtcls[i];
    #pragma unroll
    for (int k = 0; k < OUT; k++) spu[(size_t)idx*OUT + k] = (k == cls) ? 1.0f : 0.0f;
}

// ---------------------------------------------------------------- trust / finalize
__global__ void k_trust_pre(const float* __restrict__ spu, float* __restrict__ maxv,
                            int* __restrict__ amax, int* __restrict__ flags) {
    int n = blockIdx.x * 256 + threadIdx.x;
    if (n >= N) return;
    float best = spu[(size_t)n*OUT]; int bi = 0;
    #pragma unroll
    for (int k = 1; k < OUT; k++) {
        float v = spu[(size_t)n*OUT + k];
        if (v > best) { best = v; bi = k; }
    }
    maxv[n] = best; amax[n] = bi;
    if (best >= 0.9f) atomicOr(&flags[1], 1);
}

__global__ void k_finalize(const float* __restrict__ mf, const float* __restrict__ ori,
                           const float* __restrict__ maxv, const int* __restrict__ amax,
                           const int* __restrict__ flags,
                           float* __restrict__ out_trust, float* __restrict__ out_mf,
                           float* __restrict__ out_ori, float* __restrict__ out_pre) {
    int n = blockIdx.x * 256 + threadIdx.x;
    if (n >= N) return;
    float mv = maxv[n];
    bool tr = flags[1] ? (mv >= 0.9f) : (mv >= 0.85f);
    float m = tr ? 1.f : 0.f;
    out_trust[n] = m;
    const float4* src = (const float4*)(mf + (size_t)n * C);
    float4* dst = (float4*)(out_mf + (size_t)n * C);
    #pragma unroll
    for (int c = 0; c < 24; c++) {
        float4 v = src[c];
        v.x *= m; v.y *= m; v.z *= m; v.w *= m;
        dst[c] = v;
    }
    out_ori[n*3]   = ori[n*3]   * m;
    out_ori[n*3+1] = ori[n*3+1] * m;
    out_ori[n*3+2] = ori[n*3+2] * m;
    int bi = amax[n];
    #pragma unroll
    for (int k = 0; k < OUT; k++) out_pre[(size_t)n*OUT + k] = (k == bi) ? m : 0.f;
}

// ---------------------------------------------------------------- launch
extern "C" void kernel_launch(void* const* d_in, const int* in_sizes, int n_in,
                              void* d_out, int out_size, void* d_ws, size_t ws_size,
                              hipStream_t stream) {
    (void)in_sizes; (void)n_in; (void)out_size; (void)ws_size;
    const float* ssf     = (const float*)d_in[0];
    const float* scoords = (const float*)d_in[1];
    const float* gt      = (const float*)d_in[2];
    const float* svp     = (const float*)d_in[3];
    const float* mf      = (const float*)d_in[4];
    const float* ori     = (const float*)d_in[5];
    const float* posses  = (const float*)d_in[6];
    const int*   ran     = (const int*)d_in[7];

    float* out = (float*)d_out;
    float* out_trust = out;
    float* out_mf    = out_trust + N;
    float* out_ori   = out_mf + (size_t)N*C;
    float* out_pre   = out_ori + (size_t)N*3;
    float* out_uw    = out_pre + (size_t)N*OUT;
    float* out_spu   = out_uw  + (size_t)N*OUT;
    float* out_smi   = out_spu + (size_t)N*OUT;

    char* ws = (char*)d_ws;
    float*     w_diff  = (float*)(ws + OFF_DIFF);
    float*     w_al    = (float*)(ws + OFF_AL);
    float*     w_updf  = (float*)(ws + OFF_UPDF);
    int*       w_gtc   = (int*)(ws + OFF_GTC);
    int*       w_smi   = (int*)(ws + OFF_SMI);
    int*       w_perm  = (int*)(ws + OFF_PERM);
    _Float16*  w_aP    = (_Float16*)(ws + OFF_AP);
    _Float16*  w_bQ    = (_Float16*)(ws + OFF_BQ);
    _Float16*  w_mfP   = (_Float16*)(ws + OFF_MFP);
    _Float16*  w_midH  = (_Float16*)(ws + OFF_MIDH);
    float*     w_pav   = (float*)(ws + OFF_PAV);
    int*       w_pai   = (int*)(ws + OFF_PAI);
    float*     w_pb    = (float*)(ws + OFF_PB);
    float*     w_vals  = (float*)(ws + OFF_VALS);
    int*       w_pos   = (int*)(ws + OFF_POS);
    float*     w_maxv  = (float*)(ws + OFF_MAXV);
    int*       w_amax  = (int*)(ws + OFF_AMAX);
    int*       w_flags = (int*)(ws + OFF_FLAGS);
    int*       w_cnt   = (int*)(ws + OFF_CNT);
    int*       w_meta  = (int*)(ws + OFF_META);
    float4*    w_nq4   = (float4*)(ws + OFF_NQ4);
    float4*    w_sideQ = (float4*)(ws + OFF_SIDEQ);
    int*       w_sideC = (int*)(ws + OFF_SIDEC);

    hipMemsetAsync(w_pos, 0xFF, (size_t)N*4, stream);   // -1
    hipMemsetAsync(w_flags, 0, 8, stream);
    hipMemsetAsync(w_cnt, 0, OUT*4, stream);

    k_diff<<<1, 64, 0, stream>>>(posses, w_diff);
    k_prep_m<<<M/32, 64, 0, stream>>>(ssf, scoords, gt, ran, w_diff,
                                      w_al, w_aP, w_updf, w_gtc, w_cnt);
    k_prep_n<<<N/32, 64, 0, stream>>>(mf, ori, w_bQ, w_mfP, w_nq4);
    k_argmin<<<dim3(M/128, NSPA), 1024, 0, stream>>>(w_aP, w_bQ, w_al, w_nq4, w_pav, w_pai);
    k_argmin_reduce<<<M/256, 256, 0, stream>>>(w_pav, w_pai, w_smi, out_smi);
    k_scan<<<1, 64, 0, stream>>>(w_cnt, w_meta);
    k_permute<<<M/256, 256, 0, stream>>>(w_gtc, w_updf, w_meta, w_perm);
    k_gather_sorted<<<((M+256)*12)/256, 256, 0, stream>>>(w_meta, w_perm, w_smi, w_gtc,
                                                          w_mfP, w_nq4,
                                                          w_midH, w_sideQ, w_sideC);
    k_uw<<<dim3(N/128, NSPB), 1024, 0, stream>>>(w_mfP, w_midH, w_nq4,
                                                 w_sideQ, w_sideC, w_meta, w_pb);
    k_uw_final<<<N/256, 256, 0, stream>>>(w_pb, svp, out_uw, out_spu);
    k_scatter_pre<<<LG/256, 256, 0, stream>>>(w_smi, w_gtc, out_spu, w_vals, w_pos, w_flags);
    k_scatter_apply<<<LG/256, 256, 0, stream>>>(w_smi, w_gtc, w_vals, w_pos, w_flags, out_spu);
    k_trust_pre<<<N/256, 256, 0, stream>>>(out_spu, w_maxv, w_amax, w_flags);
    k_finalize<<<N/256, 256, 0, stream>>>(mf, ori, w_maxv, w_amax, w_flags,
                                          out_trust, out_mf, out_ori, out_pre);
}